// Round 17
// baseline (788.432 us; speedup 1.0000x reference)
//
#include <hip/hip_runtime.h>

#define NCN 3000
#define NPN 30000
#define TT 8
#define EE 64000
#define HH 128
#define CAPP 24
#define CAPC 64

typedef __attribute__((ext_vector_type(8))) short bf16x8;
typedef __attribute__((ext_vector_type(4))) float f32x4;

__device__ inline unsigned short f2bf(float f) {
    unsigned u = __float_as_uint(f);
    u += 0x7FFF + ((u >> 16) & 1);
    return (unsigned short)(u >> 16);
}
__device__ inline float bf2f(unsigned short h) {
    return __uint_as_float(((unsigned)h) << 16);
}
__device__ inline void split8(const float4 a, const float4 b, bf16x8& hi, bf16x8& lo) {
    float v[8] = {a.x, a.y, a.z, a.w, b.x, b.y, b.z, b.w};
#pragma unroll
    for (int i = 0; i < 8; ++i) {
        unsigned short hs = f2bf(v[i]);
        float rem = v[i] - bf2f(hs);
        hi[i] = (short)hs;
        lo[i] = (short)f2bf(rem);
    }
}
__device__ inline void add4(float4& a, const float4 b) {
    a.x += b.x; a.y += b.y; a.z += b.z; a.w += b.w;
}

// ---- linproj weight pack ----------------------------------------------------
__global__ void lin_wprep(const float* __restrict__ w, unsigned short* __restrict__ blob,
                          int K) {
    int idx = blockIdx.x * blockDim.x + threadIdx.x;
    if (idx >= HH * K) return;
    int n = idx / K, k = idx - n * K;
    int nt = n >> 4, nl = n & 15;
    int kc = k >> 5, kg = (k >> 3) & 3, kj = k & 7;
    int KC = K >> 5;
    int base = (nt * KC + kc) * 1024 + (kg * 16 + nl) * 8 + kj;
    float f = w[idx];
    unsigned short hi = f2bf(f), lo = f2bf(f - bf2f(hi));
    blob[base] = hi;
    blob[base + 512] = lo;
}

// ---- SAGE weight pack -------------------------------------------------------
__global__ void sage_wprep(const float* __restrict__ wl, const float* __restrict__ wr,
                           unsigned short* __restrict__ blob) {
    int idx = blockIdx.x * blockDim.x + threadIdx.x;
    if (idx >= HH * HH) return;
    int n = idx >> 7, k = idx & 127;
    int jt = n >> 4, nl = n & 15;
    int kc = k >> 5, kg = (k >> 3) & 3, kj = k & 7;
    int base = (jt * 4 + kc) * 2048 + (kg * 16 + nl) * 8 + kj;
    float f = wl[idx];
    unsigned short hi = f2bf(f), lo = f2bf(f - bf2f(hi));
    blob[base] = hi;
    blob[base + 512] = lo;
    f = wr[idx];
    hi = f2bf(f); lo = f2bf(f - bf2f(hi));
    blob[base + 1024] = hi;
    blob[base + 1536] = lo;
}

// ---- GRU weight pack ---------------------------------------------------------
__global__ void gru_wprep(const float* __restrict__ wih, const float* __restrict__ whh,
                          unsigned short* __restrict__ blob) {
    int idx = blockIdx.x * blockDim.x + threadIdx.x;
    if (idx >= 3 * HH * HH) return;
    int n = idx >> 7, k = idx & 127;
    int gate = n >> 7, j128 = n & 127;
    int jt = j128 >> 4, nl = j128 & 15;
    int kc = k >> 5, kg = (k >> 3) & 3, kj = k & 7;
    int base = (jt * 4 + kc) * 6144 + gate * 2048 + (kg * 16 + nl) * 8 + kj;
    float f = wih[idx];
    unsigned short hi = f2bf(f), lo = f2bf(f - bf2f(hi));
    blob[base] = hi;
    blob[base + 512] = lo;
    f = whh[idx];
    hi = f2bf(f); lo = f2bf(f - bf2f(hi));
    blob[base + 1024] = hi;
    blob[base + 1536] = lo;
}

// ---------------- input projection via split-bf16 MFMA -----------------------
template<int K>
__global__ __launch_bounds__(256, 4)
void linproj_mfma(const float* __restrict__ x, const unsigned short* __restrict__ blob,
                  const float* __restrict__ b, float* __restrict__ out, int N) {
    const int SLOTS = K / 8;
    const int KC = K / 32;
    __shared__ unsigned short lds[2 * 32 * K];
    int i0 = blockIdx.x * 32;
    int tid = threadIdx.x;
    if (tid * 8 < 32 * K) {
        int linear = tid * 8;
        int r = linear / K, k0 = linear % K;
        int row = i0 + r; if (row >= N) row = N - 1;
        float4 a = *(const float4*)&x[(size_t)row * K + k0];
        float4 b4 = *(const float4*)&x[(size_t)row * K + k0 + 4];
        bf16x8 hi, lo;
        split8(a, b4, hi, lo);
        int dst8 = (r * SLOTS + ((k0 >> 3) ^ (r & (SLOTS - 1)))) * 8;
        *(bf16x8*)&lds[dst8] = hi;
        *(bf16x8*)&lds[32 * K + dst8] = lo;
    }
    __syncthreads();
    int wid = tid >> 6, lane = tid & 63;
    int jt0 = wid * 2;
    f32x4 acc[2][2];
#pragma unroll
    for (int a = 0; a < 2; ++a)
#pragma unroll
        for (int m = 0; m < 2; ++m) acc[a][m] = (f32x4){0.f, 0.f, 0.f, 0.f};
#pragma unroll
    for (int kc = 0; kc < KC; ++kc) {
        bf16x8 ah[2], al[2];
#pragma unroll
        for (int mt = 0; mt < 2; ++mt) {
            int rl = mt * 16 + (lane & 15);
            int slot = (kc * 4 + (lane >> 4)) ^ (rl & (SLOTS - 1));
            int aoff = (rl * SLOTS + slot) * 8;
            ah[mt] = *(const bf16x8*)&lds[aoff];
            al[mt] = *(const bf16x8*)&lds[32 * K + aoff];
        }
#pragma unroll
        for (int jj = 0; jj < 2; ++jj) {
            int bbase = ((jt0 + jj) * KC + kc) * 1024 + lane * 8;
            bf16x8 f0 = *(const bf16x8*)&blob[bbase];
            bf16x8 f1 = *(const bf16x8*)&blob[bbase + 512];
#pragma unroll
            for (int mt = 0; mt < 2; ++mt) {
                acc[jj][mt] = __builtin_amdgcn_mfma_f32_16x16x32_bf16(ah[mt], f0, acc[jj][mt], 0, 0, 0);
                acc[jj][mt] = __builtin_amdgcn_mfma_f32_16x16x32_bf16(al[mt], f0, acc[jj][mt], 0, 0, 0);
                acc[jj][mt] = __builtin_amdgcn_mfma_f32_16x16x32_bf16(ah[mt], f1, acc[jj][mt], 0, 0, 0);
            }
        }
    }
#pragma unroll
    for (int jj = 0; jj < 2; ++jj) {
        int j = (jt0 + jj) * 16 + (lane & 15);
        float bv = b[j];
#pragma unroll
        for (int mt = 0; mt < 2; ++mt) {
#pragma unroll
            for (int q = 0; q < 4; ++q) {
                int r_loc = mt * 16 + (lane >> 4) * 4 + q;
                int row = i0 + r_loc;
                if (row < N) out[(size_t)row * HH + j] = acc[jj][mt][q] + bv;
            }
        }
    }
}

// ---------------- edge bucket build, all timesteps ---------------------------
__global__ void build_kernel(const int* __restrict__ es, const int* __restrict__ ed,
                             int* __restrict__ cntP, int* __restrict__ cntC,
                             int* __restrict__ listP, int* __restrict__ listC) {
    int g = blockIdx.x * 256 + threadIdx.x;
    if (g >= TT * EE) return;
    int t = g / EE;
    int s = es[g], d = ed[g];
    int pP = atomicAdd(&cntP[t * NPN + d], 1);
    if (pP < CAPP) listP[((size_t)t * NPN + d) * CAPP + pP] = s;
    int pC = atomicAdd(&cntC[t * NCN + s], 1);
    if (pC < CAPC) listC[((size_t)t * NCN + s) * CAPC + pC] = d;
}

// ---- staging M=64 (512 threads): 2 rows/thread, gather-mean + self ----------
// LDS regions (ushort units): msg_hi 0, msg_lo 8192, self_hi 16384, self_lo 24576
__device__ inline void stage64(unsigned short* lds, const int* cnt, const int* list,
                               int CAP, const float* gsrc, const float* hin,
                               int i0, int N, int tid) {
    int r0 = tid >> 4, k0 = (tid & 15) * 8;
#pragma unroll
    for (int h = 0; h < 2; ++h) {
        int r = r0 + h * 32;
        int row = i0 + r; if (row >= N) row = N - 1;
        float4 ha = *(const float4*)&hin[(size_t)row * HH + k0];
        float4 hb = *(const float4*)&hin[(size_t)row * HH + k0 + 4];
        int ntru = cnt[row];
        int n = ntru > CAP ? CAP : ntru;
        const int* lst = &list[(size_t)row * CAP];
        float4 a0 = {0,0,0,0}, b0 = {0,0,0,0}, a1 = {0,0,0,0}, b1 = {0,0,0,0};
        float4 a2 = {0,0,0,0}, b2 = {0,0,0,0}, a3 = {0,0,0,0}, b3 = {0,0,0,0};
        int e = 0;
        for (; e + 4 <= n; e += 4) {
            int4 ss = *(const int4*)&lst[e];
            const float4* p0 = (const float4*)&gsrc[(size_t)ss.x * HH + k0];
            const float4* p1 = (const float4*)&gsrc[(size_t)ss.y * HH + k0];
            const float4* p2 = (const float4*)&gsrc[(size_t)ss.z * HH + k0];
            const float4* p3 = (const float4*)&gsrc[(size_t)ss.w * HH + k0];
            float4 u0 = p0[0], v0 = p0[1];
            float4 u1 = p1[0], v1 = p1[1];
            float4 u2 = p2[0], v2 = p2[1];
            float4 u3 = p3[0], v3 = p3[1];
            add4(a0, u0); add4(b0, v0);
            add4(a1, u1); add4(b1, v1);
            add4(a2, u2); add4(b2, v2);
            add4(a3, u3); add4(b3, v3);
        }
        for (; e < n; ++e) {
            int s = lst[e];
            const float4* p0 = (const float4*)&gsrc[(size_t)s * HH + k0];
            float4 u0 = p0[0], v0 = p0[1];
            add4(a0, u0); add4(b0, v0);
        }
        add4(a0, a1); add4(b0, b1);
        add4(a2, a3); add4(b2, b3);
        add4(a0, a2); add4(b0, b2);
        float inv = 1.0f / fmaxf((float)ntru, 1.0f);
        a0.x *= inv; a0.y *= inv; a0.z *= inv; a0.w *= inv;
        b0.x *= inv; b0.y *= inv; b0.z *= inv; b0.w *= inv;
        int dst8 = (r * 16 + ((k0 >> 3) ^ (r & 7))) * 8;
        bf16x8 hi, lo;
        split8(a0, b0, hi, lo);
        *(bf16x8*)&lds[dst8] = hi;
        *(bf16x8*)&lds[8192 + dst8] = lo;
        split8(ha, hb, hi, lo);
        *(bf16x8*)&lds[16384 + dst8] = hi;
        *(bf16x8*)&lds[24576 + dst8] = lo;
    }
}

// ========= PAIR kernel (M=64): sage2+gru(t_gru) ∥ sage layer-1(t_sage) =======
// 512 threads / 8 waves; wave wid owns jt = wid across 4 m-tiles (64 rows).
__global__ __launch_bounds__(512, 2)
void pair_kernel(int bndGC, int bndSC, int bndGP,
                 const int* __restrict__ cntP_all, const int* __restrict__ cntC_all,
                 const int* __restrict__ listP_all, const int* __restrict__ listC_all,
                 const float* __restrict__ hp_all, const float* __restrict__ hc_all,
                 float* __restrict__ hp1A, float* __restrict__ hc1A,
                 float* __restrict__ hp1B, float* __restrict__ hc1B,
                 int t_gru, int t_sage,
                 const unsigned short* __restrict__ blob_s1cp, const float* __restrict__ bl1_cp,
                 const unsigned short* __restrict__ blob_s1pc, const float* __restrict__ bl1_pc,
                 const unsigned short* __restrict__ blob_s2cp, const float* __restrict__ bl2_cp,
                 const unsigned short* __restrict__ blob_s2pc, const float* __restrict__ bl2_pc,
                 const unsigned short* __restrict__ blob_gp,
                 const float* __restrict__ b_ih_p, const float* __restrict__ b_hh_p,
                 const unsigned short* __restrict__ blob_gc,
                 const float* __restrict__ b_ih_c, const float* __restrict__ b_hh_c,
                 float* __restrict__ h_c, float* __restrict__ h_p) {
    __shared__ unsigned short lds[4 * 8192];   // 64 KB
    int bid = blockIdx.x;
    bool isGru, isC;
    int idx;
    if (bid < bndGC)      { isGru = true;  isC = true;  idx = bid; }
    else if (bid < bndSC) { isGru = false; isC = true;  idx = bid - bndGC; }
    else if (bid < bndGP) { isGru = true;  isC = false; idx = bid - bndSC; }
    else                  { isGru = false; isC = false; idx = bid - bndGP; }

    float* hp1_g = (t_gru & 1) ? hp1B : hp1A;
    float* hc1_g = (t_gru & 1) ? hc1B : hc1A;
    float* hp1_s = (t_sage & 1) ? hp1B : hp1A;
    float* hc1_s = (t_sage & 1) ? hc1B : hc1A;

    const int* cnt; const int* list; int CAP;
    const float* gsrc; const float* hin;
    const unsigned short* sblob; const float* sbl;
    const unsigned short* gblob; const float* bih; const float* bhh;
    float* outp;
    int N, i0 = idx * 64;
    if (isGru) {
        if (isC) {
            cnt = cntC_all + (size_t)t_gru * NCN;
            list = listC_all + (size_t)t_gru * NCN * CAPC; CAP = CAPC;
            gsrc = hp1_g; hin = hc1_g;
            sblob = blob_s2pc; sbl = bl2_pc;
            gblob = blob_gc; bih = b_ih_c; bhh = b_hh_c;
            outp = h_c; N = NCN;
        } else {
            cnt = cntP_all + (size_t)t_gru * NPN;
            list = listP_all + (size_t)t_gru * NPN * CAPP; CAP = CAPP;
            gsrc = hc1_g; hin = hp1_g;
            sblob = blob_s2cp; sbl = bl2_cp;
            gblob = blob_gp; bih = b_ih_p; bhh = b_hh_p;
            outp = h_p; N = NPN;
        }
    } else {
        const float* hp_t = hp_all + (size_t)t_sage * NPN * HH;
        const float* hc_t = hc_all + (size_t)t_sage * NCN * HH;
        if (isC) {
            cnt = cntC_all + (size_t)t_sage * NCN;
            list = listC_all + (size_t)t_sage * NCN * CAPC; CAP = CAPC;
            gsrc = hp_t; hin = hc_t;
            sblob = blob_s1pc; sbl = bl1_pc;
            gblob = nullptr; bih = nullptr; bhh = nullptr;
            outp = hc1_s; N = NCN;
        } else {
            cnt = cntP_all + (size_t)t_sage * NPN;
            list = listP_all + (size_t)t_sage * NPN * CAPP; CAP = CAPP;
            gsrc = hc_t; hin = hp_t;
            sblob = blob_s1cp; sbl = bl1_cp;
            gblob = nullptr; bih = nullptr; bhh = nullptr;
            outp = hp1_s; N = NPN;
        }
    }
    int tid = threadIdx.x;
    int wid = tid >> 6, lane = tid & 63;
    int jt = wid;
    int sr = tid >> 4, sk0 = (tid & 15) * 8;

    // ---- hprev preload (gru role): 2 rows ----------------------------------
    float4 hpre[2][2];
    if (isGru) {
#pragma unroll
        for (int h = 0; h < 2; ++h) {
            int row = i0 + sr + h * 32; if (row >= N) row = N - 1;
            hpre[h][0] = *(const float4*)&outp[(size_t)row * HH + sk0];
            hpre[h][1] = *(const float4*)&outp[(size_t)row * HH + sk0 + 4];
        }
    }

    stage64(lds, cnt, list, CAP, gsrc, hin, i0, N, tid);
    __syncthreads();

    // ---- sage MFMA: wave owns jt, 4 m-tiles --------------------------------
    f32x4 acc[4];
#pragma unroll
    for (int m = 0; m < 4; ++m) acc[m] = (f32x4){0.f, 0.f, 0.f, 0.f};
#pragma unroll
    for (int kc = 0; kc < 4; ++kc) {
        int bbase = (jt * 4 + kc) * 2048 + lane * 8;
        bf16x8 f0 = *(const bf16x8*)&sblob[bbase];
        bf16x8 f1 = *(const bf16x8*)&sblob[bbase + 512];
        bf16x8 f2 = *(const bf16x8*)&sblob[bbase + 1024];
        bf16x8 f3 = *(const bf16x8*)&sblob[bbase + 1536];
#pragma unroll
        for (int mt = 0; mt < 4; ++mt) {
            int rl = mt * 16 + (lane & 15);
            int aoff = (rl * 16 + ((kc * 4 + (lane >> 4)) ^ (rl & 7))) * 8;
            bf16x8 amh = *(const bf16x8*)&lds[aoff];
            bf16x8 aml = *(const bf16x8*)&lds[8192 + aoff];
            bf16x8 ahh = *(const bf16x8*)&lds[16384 + aoff];
            bf16x8 ahl = *(const bf16x8*)&lds[24576 + aoff];
            acc[mt] = __builtin_amdgcn_mfma_f32_16x16x32_bf16(amh, f0, acc[mt], 0, 0, 0);
            acc[mt] = __builtin_amdgcn_mfma_f32_16x16x32_bf16(aml, f0, acc[mt], 0, 0, 0);
            acc[mt] = __builtin_amdgcn_mfma_f32_16x16x32_bf16(amh, f1, acc[mt], 0, 0, 0);
            acc[mt] = __builtin_amdgcn_mfma_f32_16x16x32_bf16(ahh, f2, acc[mt], 0, 0, 0);
            acc[mt] = __builtin_amdgcn_mfma_f32_16x16x32_bf16(ahl, f2, acc[mt], 0, 0, 0);
            acc[mt] = __builtin_amdgcn_mfma_f32_16x16x32_bf16(ahh, f3, acc[mt], 0, 0, 0);
        }
    }
    int j = jt * 16 + (lane & 15);

    if (!isGru) {
        float bv = sbl[j];
#pragma unroll
        for (int mt = 0; mt < 4; ++mt) {
#pragma unroll
            for (int q = 0; q < 4; ++q) {
                int r_loc = mt * 16 + (lane >> 4) * 4 + q;
                int row = i0 + r_loc;
                if (row >= N) continue;
                float v = fmaxf(acc[mt][q] + bv, 0.0f);
                outp[(size_t)row * HH + j] = v;
            }
        }
        return;
    }

    // ---- GRU phase C: x = acc + bias into regions 0/1; hprev into 2/3 ------
    __syncthreads();
    {
        float bv = sbl[j];
#pragma unroll
        for (int mt = 0; mt < 4; ++mt) {
#pragma unroll
            for (int q = 0; q < 4; ++q) {
                int r_loc = mt * 16 + (lane >> 4) * 4 + q;
                float v = acc[mt][q] + bv;
                unsigned short hi = f2bf(v);
                unsigned short lo = f2bf(v - bf2f(hi));
                int off = (r_loc * 16 + ((j >> 3) ^ (r_loc & 7))) * 8 + (j & 7);
                lds[off] = hi;
                lds[8192 + off] = lo;
            }
        }
#pragma unroll
        for (int h = 0; h < 2; ++h) {
            int r = sr + h * 32;
            int dst8 = (r * 16 + ((sk0 >> 3) ^ (r & 7))) * 8;
            bf16x8 hi, lo;
            split8(hpre[h][0], hpre[h][1], hi, lo);
            *(bf16x8*)&lds[16384 + dst8] = hi;
            *(bf16x8*)&lds[24576 + dst8] = lo;
        }
    }
    __syncthreads();

    // ---- GRU MFMA: per kc load all 12 B-frags once; 4 m-tiles --------------
    f32x4 ar[4], az[4], an[4], ahn[4];
#pragma unroll
    for (int m = 0; m < 4; ++m) {
        ar[m] = (f32x4){0.f, 0.f, 0.f, 0.f};
        az[m] = (f32x4){0.f, 0.f, 0.f, 0.f};
        an[m] = (f32x4){0.f, 0.f, 0.f, 0.f};
        ahn[m] = (f32x4){0.f, 0.f, 0.f, 0.f};
    }
#pragma unroll
    for (int kc = 0; kc < 4; ++kc) {
        int bbase = (jt * 4 + kc) * 6144 + lane * 8;
        bf16x8 r0 = *(const bf16x8*)&gblob[bbase];
        bf16x8 r1 = *(const bf16x8*)&gblob[bbase + 512];
        bf16x8 r2 = *(const bf16x8*)&gblob[bbase + 1024];
        bf16x8 r3 = *(const bf16x8*)&gblob[bbase + 1536];
        bf16x8 z0 = *(const bf16x8*)&gblob[bbase + 2048];
        bf16x8 z1 = *(const bf16x8*)&gblob[bbase + 2560];
        bf16x8 z2 = *(const bf16x8*)&gblob[bbase + 3072];
        bf16x8 z3 = *(const bf16x8*)&gblob[bbase + 3584];
        bf16x8 n0 = *(const bf16x8*)&gblob[bbase + 4096];
        bf16x8 n1 = *(const bf16x8*)&gblob[bbase + 4608];
        bf16x8 n2 = *(const bf16x8*)&gblob[bbase + 5120];
        bf16x8 n3 = *(const bf16x8*)&gblob[bbase + 5632];
#pragma unroll
        for (int mt = 0; mt < 4; ++mt) {
            int rl = mt * 16 + (lane & 15);
            int aoff = (rl * 16 + ((kc * 4 + (lane >> 4)) ^ (rl & 7))) * 8;
            bf16x8 axh = *(const bf16x8*)&lds[aoff];
            bf16x8 axl = *(const bf16x8*)&lds[8192 + aoff];
            bf16x8 ahh = *(const bf16x8*)&lds[16384 + aoff];
            bf16x8 ahl = *(const bf16x8*)&lds[24576 + aoff];
            ar[mt] = __builtin_amdgcn_mfma_f32_16x16x32_bf16(axh, r0, ar[mt], 0, 0, 0);
            ar[mt] = __builtin_amdgcn_mfma_f32_16x16x32_bf16(axl, r0, ar[mt], 0, 0, 0);
            ar[mt] = __builtin_amdgcn_mfma_f32_16x16x32_bf16(axh, r1, ar[mt], 0, 0, 0);
            ar[mt] = __builtin_amdgcn_mfma_f32_16x16x32_bf16(ahh, r2, ar[mt], 0, 0, 0);
            ar[mt] = __builtin_amdgcn_mfma_f32_16x16x32_bf16(ahl, r2, ar[mt], 0, 0, 0);
            ar[mt] = __builtin_amdgcn_mfma_f32_16x16x32_bf16(ahh, r3, ar[mt], 0, 0, 0);
            az[mt] = __builtin_amdgcn_mfma_f32_16x16x32_bf16(axh, z0, az[mt], 0, 0, 0);
            az[mt] = __builtin_amdgcn_mfma_f32_16x16x32_bf16(axl, z0, az[mt], 0, 0, 0);
            az[mt] = __builtin_amdgcn_mfma_f32_16x16x32_bf16(axh, z1, az[mt], 0, 0, 0);
            az[mt] = __builtin_amdgcn_mfma_f32_16x16x32_bf16(ahh, z2, az[mt], 0, 0, 0);
            az[mt] = __builtin_amdgcn_mfma_f32_16x16x32_bf16(ahl, z2, az[mt], 0, 0, 0);
            az[mt] = __builtin_amdgcn_mfma_f32_16x16x32_bf16(ahh, z3, az[mt], 0, 0, 0);
            an[mt] = __builtin_amdgcn_mfma_f32_16x16x32_bf16(axh, n0, an[mt], 0, 0, 0);
            an[mt] = __builtin_amdgcn_mfma_f32_16x16x32_bf16(axl, n0, an[mt], 0, 0, 0);
            an[mt] = __builtin_amdgcn_mfma_f32_16x16x32_bf16(axh, n1, an[mt], 0, 0, 0);
            ahn[mt] = __builtin_amdgcn_mfma_f32_16x16x32_bf16(ahh, n2, ahn[mt], 0, 0, 0);
            ahn[mt] = __builtin_amdgcn_mfma_f32_16x16x32_bf16(ahl, n2, ahn[mt], 0, 0, 0);
            ahn[mt] = __builtin_amdgcn_mfma_f32_16x16x32_bf16(ahh, n3, ahn[mt], 0, 0, 0);
        }
    }
    {
        float br = bih[j] + bhh[j];
        float bz = bih[HH + j] + bhh[HH + j];
        float bn_i = bih[2 * HH + j];
        float bn_h = bhh[2 * HH + j];
#pragma unroll
        for (int mt = 0; mt < 4; ++mt) {
#pragma unroll
            for (int q = 0; q < 4; ++q) {
                int r_loc = mt * 16 + (lane >> 4) * 4 + q;
                int row = i0 + r_loc;
                if (row >= N) continue;
                float pr = ar[mt][q] + br;
                float pz = az[mt][q] + bz;
                float pn = an[mt][q] + bn_i;
                float phn = ahn[mt][q] + bn_h;
                float rg = 1.0f / (1.0f + __expf(-pr));
                float zg = 1.0f / (1.0f + __expf(-pz));
                float ng = tanhf(pn + rg * phn);
                int eo = (r_loc * 16 + ((j >> 3) ^ (r_loc & 7))) * 8 + (j & 7);
                float hprev = bf2f(lds[16384 + eo]) + bf2f(lds[24576 + eo]);
                outp[(size_t)row * HH + j] = (1.0f - zg) * ng + zg * hprev;
            }
        }
    }
}

extern "C" void kernel_launch(void* const* d_in, const int* in_sizes, int n_in,
                              void* d_out, int out_size, void* d_ws, size_t ws_size,
                              hipStream_t stream) {
    const float* xc     = (const float*)d_in[0];
    const float* xp     = (const float*)d_in[1];
    const int*   esrc   = (const int*)d_in[2];
    const int*   edst   = (const int*)d_in[3];
    const float* w_clin = (const float*)d_in[4];
    const float* b_clin = (const float*)d_in[5];
    const float* w_plin = (const float*)d_in[6];
    const float* b_plin = (const float*)d_in[7];
    const float* wl1_cp = (const float*)d_in[8];
    const float* wr1_cp = (const float*)d_in[9];
    const float* wl1_pc = (const float*)d_in[10];
    const float* wr1_pc = (const float*)d_in[11];
    const float* wl2_cp = (const float*)d_in[12];
    const float* wr2_cp = (const float*)d_in[13];
    const float* wl2_pc = (const float*)d_in[14];
    const float* wr2_pc = (const float*)d_in[15];
    const float* bl1_cp = (const float*)d_in[16];
    const float* bl1_pc = (const float*)d_in[17];
    const float* bl2_cp = (const float*)d_in[18];
    const float* bl2_pc = (const float*)d_in[19];
    const float* w_ih_c = (const float*)d_in[20];
    const float* w_hh_c = (const float*)d_in[21];
    const float* w_ih_p = (const float*)d_in[22];
    const float* w_hh_p = (const float*)d_in[23];
    const float* b_ih_c = (const float*)d_in[24];
    const float* b_hh_c = (const float*)d_in[25];
    const float* b_ih_p = (const float*)d_in[26];
    const float* b_hh_p = (const float*)d_in[27];

    float* ws      = (float*)d_ws;
    float* hp_all  = ws;
    float* hc_all  = hp_all + (size_t)TT * NPN * HH;
    float* hp1A    = hc_all + (size_t)TT * NCN * HH;
    float* hc1A    = hp1A + (size_t)NPN * HH;
    float* hp1B    = hc1A + (size_t)NCN * HH;
    float* hc1B    = hp1B + (size_t)NPN * HH;
    int*   cntP_all = (int*)(hc1B + (size_t)NCN * HH);
    int*   cntC_all = cntP_all + (size_t)TT * NPN;
    int*   listP_all = cntC_all + (size_t)TT * NCN;
    int*   listC_all = listP_all + (size_t)TT * NPN * CAPP;

    unsigned short* fw = (unsigned short*)(listC_all + (size_t)TT * NCN * CAPC);
    const int SB = 65536;
    const int GB = 196608;
    unsigned short* blob_s1cp = fw;
    unsigned short* blob_s1pc = blob_s1cp + SB;
    unsigned short* blob_s2cp = blob_s1pc + SB;
    unsigned short* blob_s2pc = blob_s2cp + SB;
    unsigned short* blob_gp   = blob_s2pc + SB;
    unsigned short* blob_gc   = blob_gp + GB;
    unsigned short* blob_lc   = blob_gc + GB;
    unsigned short* blob_lp   = blob_lc + 8192;

    float* h_c = (float*)d_out;
    float* h_p = h_c + (size_t)NCN * HH;

    {
        const int B = 256;
        int gs = (HH * HH + B - 1) / B;
        sage_wprep<<<gs, B, 0, stream>>>(wl1_cp, wr1_cp, blob_s1cp);
        sage_wprep<<<gs, B, 0, stream>>>(wl1_pc, wr1_pc, blob_s1pc);
        sage_wprep<<<gs, B, 0, stream>>>(wl2_cp, wr2_cp, blob_s2cp);
        sage_wprep<<<gs, B, 0, stream>>>(wl2_pc, wr2_pc, blob_s2pc);
        int gg = (3 * HH * HH + B - 1) / B;
        gru_wprep<<<gg, B, 0, stream>>>(w_ih_p, w_hh_p, blob_gp);
        gru_wprep<<<gg, B, 0, stream>>>(w_ih_c, w_hh_c, blob_gc);
        lin_wprep<<<(HH * 32 + B - 1) / B, B, 0, stream>>>(w_clin, blob_lc, 32);
        lin_wprep<<<(HH * 64 + B - 1) / B, B, 0, stream>>>(w_plin, blob_lp, 64);
    }

    hipMemsetAsync(d_out, 0, (size_t)out_size * sizeof(float), stream);
    hipMemsetAsync(cntP_all, 0, (size_t)TT * (NPN + NCN) * sizeof(int), stream);

    build_kernel<<<(TT * EE + 255) / 256, 256, 0, stream>>>(esrc, edst, cntP_all, cntC_all,
                                                            listP_all, listC_all);
    linproj_mfma<32><<<(TT * NCN + 31) / 32, 256, 0, stream>>>(xc, blob_lc, b_clin, hc_all, TT * NCN);
    linproj_mfma<64><<<(TT * NPN + 31) / 32, 256, 0, stream>>>(xp, blob_lp, b_plin, hp_all, TT * NPN);

    const int gP64 = (NPN + 63) / 64, gC64 = (NCN + 63) / 64;

    for (int k = 0; k <= TT; ++k) {
        int hasG = (k >= 1), hasS = (k < TT);
        int t_g = hasG ? (k - 1) : 0;
        int t_s = hasS ? k : 0;
        int bndGC = hasG ? gC64 : 0;
        int bndSC = bndGC + (hasS ? gC64 : 0);
        int bndGP = bndSC + (hasG ? gP64 : 0);
        int grid  = bndGP + (hasS ? gP64 : 0);
        pair_kernel<<<grid, 512, 0, stream>>>(
            bndGC, bndSC, bndGP,
            cntP_all, cntC_all, listP_all, listC_all,
            hp_all, hc_all, hp1A, hc1A, hp1B, hc1B,
            t_g, t_s,
            blob_s1cp, bl1_cp, blob_s1pc, bl1_pc,
            blob_s2cp, bl2_cp, blob_s2pc, bl2_pc,
            blob_gp, b_ih_p, b_hh_p,
            blob_gc, b_ih_c, b_hh_c,
            h_c, h_p);
    }
}

// Round 18
// 764.068 us; speedup vs baseline: 1.0319x; 1.0319x over previous
//
#include <hip/hip_runtime.h>

#define NCN 3000
#define NPN 30000
#define TT 8
#define EE 64000
#define HH 128
#define CAPP 24
#define CAPC 64

typedef __attribute__((ext_vector_type(8))) short bf16x8;
typedef __attribute__((ext_vector_type(4))) float f32x4;

__device__ inline unsigned short f2bf(float f) {
    unsigned u = __float_as_uint(f);
    u += 0x7FFF + ((u >> 16) & 1);
    return (unsigned short)(u >> 16);
}
__device__ inline float bf2f(unsigned short h) {
    return __uint_as_float(((unsigned)h) << 16);
}
__device__ inline void split8(const float4 a, const float4 b, bf16x8& hi, bf16x8& lo) {
    float v[8] = {a.x, a.y, a.z, a.w, b.x, b.y, b.z, b.w};
#pragma unroll
    for (int i = 0; i < 8; ++i) {
        unsigned short hs = f2bf(v[i]);
        float rem = v[i] - bf2f(hs);
        hi[i] = (short)hs;
        lo[i] = (short)f2bf(rem);
    }
}
__device__ inline void add4(float4& a, const float4 b) {
    a.x += b.x; a.y += b.y; a.z += b.z; a.w += b.w;
}

// ---- linproj weight pack ----------------------------------------------------
__global__ void lin_wprep(const float* __restrict__ w, unsigned short* __restrict__ blob,
                          int K) {
    int idx = blockIdx.x * blockDim.x + threadIdx.x;
    if (idx >= HH * K) return;
    int n = idx / K, k = idx - n * K;
    int nt = n >> 4, nl = n & 15;
    int kc = k >> 5, kg = (k >> 3) & 3, kj = k & 7;
    int KC = K >> 5;
    int base = (nt * KC + kc) * 1024 + (kg * 16 + nl) * 8 + kj;
    float f = w[idx];
    unsigned short hi = f2bf(f), lo = f2bf(f - bf2f(hi));
    blob[base] = hi;
    blob[base + 512] = lo;
}

// ---- SAGE weight pack -------------------------------------------------------
__global__ void sage_wprep(const float* __restrict__ wl, const float* __restrict__ wr,
                           unsigned short* __restrict__ blob) {
    int idx = blockIdx.x * blockDim.x + threadIdx.x;
    if (idx >= HH * HH) return;
    int n = idx >> 7, k = idx & 127;
    int jt = n >> 4, nl = n & 15;
    int kc = k >> 5, kg = (k >> 3) & 3, kj = k & 7;
    int base = (jt * 4 + kc) * 2048 + (kg * 16 + nl) * 8 + kj;
    float f = wl[idx];
    unsigned short hi = f2bf(f), lo = f2bf(f - bf2f(hi));
    blob[base] = hi;
    blob[base + 512] = lo;
    f = wr[idx];
    hi = f2bf(f); lo = f2bf(f - bf2f(hi));
    blob[base + 1024] = hi;
    blob[base + 1536] = lo;
}

// ---- GRU weight pack ---------------------------------------------------------
__global__ void gru_wprep(const float* __restrict__ wih, const float* __restrict__ whh,
                          unsigned short* __restrict__ blob) {
    int idx = blockIdx.x * blockDim.x + threadIdx.x;
    if (idx >= 3 * HH * HH) return;
    int n = idx >> 7, k = idx & 127;
    int gate = n >> 7, j128 = n & 127;
    int jt = j128 >> 4, nl = j128 & 15;
    int kc = k >> 5, kg = (k >> 3) & 3, kj = k & 7;
    int base = (jt * 4 + kc) * 6144 + gate * 2048 + (kg * 16 + nl) * 8 + kj;
    float f = wih[idx];
    unsigned short hi = f2bf(f), lo = f2bf(f - bf2f(hi));
    blob[base] = hi;
    blob[base + 512] = lo;
    f = whh[idx];
    hi = f2bf(f); lo = f2bf(f - bf2f(hi));
    blob[base + 1024] = hi;
    blob[base + 1536] = lo;
}

// ---------------- input projection via split-bf16 MFMA -----------------------
template<int K>
__global__ __launch_bounds__(256, 4)
void linproj_mfma(const float* __restrict__ x, const unsigned short* __restrict__ blob,
                  const float* __restrict__ b, float* __restrict__ out, int N) {
    const int SLOTS = K / 8;
    const int KC = K / 32;
    __shared__ unsigned short lds[2 * 32 * K];
    int i0 = blockIdx.x * 32;
    int tid = threadIdx.x;
    if (tid * 8 < 32 * K) {
        int linear = tid * 8;
        int r = linear / K, k0 = linear % K;
        int row = i0 + r; if (row >= N) row = N - 1;
        float4 a = *(const float4*)&x[(size_t)row * K + k0];
        float4 b4 = *(const float4*)&x[(size_t)row * K + k0 + 4];
        bf16x8 hi, lo;
        split8(a, b4, hi, lo);
        int dst8 = (r * SLOTS + ((k0 >> 3) ^ (r & (SLOTS - 1)))) * 8;
        *(bf16x8*)&lds[dst8] = hi;
        *(bf16x8*)&lds[32 * K + dst8] = lo;
    }
    __syncthreads();
    int wid = tid >> 6, lane = tid & 63;
    int jt0 = wid * 2;
    f32x4 acc[2][2];
#pragma unroll
    for (int a = 0; a < 2; ++a)
#pragma unroll
        for (int m = 0; m < 2; ++m) acc[a][m] = (f32x4){0.f, 0.f, 0.f, 0.f};
#pragma unroll
    for (int kc = 0; kc < KC; ++kc) {
        bf16x8 ah[2], al[2];
#pragma unroll
        for (int mt = 0; mt < 2; ++mt) {
            int rl = mt * 16 + (lane & 15);
            int slot = (kc * 4 + (lane >> 4)) ^ (rl & (SLOTS - 1));
            int aoff = (rl * SLOTS + slot) * 8;
            ah[mt] = *(const bf16x8*)&lds[aoff];
            al[mt] = *(const bf16x8*)&lds[32 * K + aoff];
        }
#pragma unroll
        for (int jj = 0; jj < 2; ++jj) {
            int bbase = ((jt0 + jj) * KC + kc) * 1024 + lane * 8;
            bf16x8 f0 = *(const bf16x8*)&blob[bbase];
            bf16x8 f1 = *(const bf16x8*)&blob[bbase + 512];
#pragma unroll
            for (int mt = 0; mt < 2; ++mt) {
                acc[jj][mt] = __builtin_amdgcn_mfma_f32_16x16x32_bf16(ah[mt], f0, acc[jj][mt], 0, 0, 0);
                acc[jj][mt] = __builtin_amdgcn_mfma_f32_16x16x32_bf16(al[mt], f0, acc[jj][mt], 0, 0, 0);
                acc[jj][mt] = __builtin_amdgcn_mfma_f32_16x16x32_bf16(ah[mt], f1, acc[jj][mt], 0, 0, 0);
            }
        }
    }
#pragma unroll
    for (int jj = 0; jj < 2; ++jj) {
        int j = (jt0 + jj) * 16 + (lane & 15);
        float bv = b[j];
#pragma unroll
        for (int mt = 0; mt < 2; ++mt) {
#pragma unroll
            for (int q = 0; q < 4; ++q) {
                int r_loc = mt * 16 + (lane >> 4) * 4 + q;
                int row = i0 + r_loc;
                if (row < N) out[(size_t)row * HH + j] = acc[jj][mt][q] + bv;
            }
        }
    }
}

// ---------------- edge bucket build, all timesteps ---------------------------
__global__ void build_kernel(const int* __restrict__ es, const int* __restrict__ ed,
                             int* __restrict__ cntP, int* __restrict__ cntC,
                             int* __restrict__ listP, int* __restrict__ listC) {
    int g = blockIdx.x * 256 + threadIdx.x;
    if (g >= TT * EE) return;
    int t = g / EE;
    int s = es[g], d = ed[g];
    int pP = atomicAdd(&cntP[t * NPN + d], 1);
    if (pP < CAPP) listP[((size_t)t * NPN + d) * CAPP + pP] = s;
    int pC = atomicAdd(&cntC[t * NCN + s], 1);
    if (pC < CAPC) listC[((size_t)t * NCN + s) * CAPC + pC] = d;
}

// ---- staging (512 threads): gather-mean (8-deep ILP) + self -> LDS ----------
__device__ inline void stage512(unsigned short* lds, const int* cnt, const int* list,
                                int CAP, const float* gsrc, const float* hin,
                                int i0, int N, int tid) {
    int r = tid >> 4, k0 = (tid & 15) * 8;
    int row = i0 + r; if (row >= N) row = N - 1;
    float4 ha = *(const float4*)&hin[(size_t)row * HH + k0];
    float4 hb = *(const float4*)&hin[(size_t)row * HH + k0 + 4];
    int ntru = cnt[row];
    int n = ntru > CAP ? CAP : ntru;
    const int* lst = &list[(size_t)row * CAP];
    float4 a0 = {0,0,0,0}, b0 = {0,0,0,0}, a1 = {0,0,0,0}, b1 = {0,0,0,0};
    float4 a2 = {0,0,0,0}, b2 = {0,0,0,0}, a3 = {0,0,0,0}, b3 = {0,0,0,0};
    int e = 0;
    // 8-edge chunks: 16 row-loads in flight per exposed latency
    for (; e + 8 <= n; e += 8) {
        int4 sa = *(const int4*)&lst[e];
        int4 sb = *(const int4*)&lst[e + 4];
        const float4* q0 = (const float4*)&gsrc[(size_t)sa.x * HH + k0];
        const float4* q1 = (const float4*)&gsrc[(size_t)sa.y * HH + k0];
        const float4* q2 = (const float4*)&gsrc[(size_t)sa.z * HH + k0];
        const float4* q3 = (const float4*)&gsrc[(size_t)sa.w * HH + k0];
        const float4* q4 = (const float4*)&gsrc[(size_t)sb.x * HH + k0];
        const float4* q5 = (const float4*)&gsrc[(size_t)sb.y * HH + k0];
        const float4* q6 = (const float4*)&gsrc[(size_t)sb.z * HH + k0];
        const float4* q7 = (const float4*)&gsrc[(size_t)sb.w * HH + k0];
        float4 u0 = q0[0], v0 = q0[1];
        float4 u1 = q1[0], v1 = q1[1];
        float4 u2 = q2[0], v2 = q2[1];
        float4 u3 = q3[0], v3 = q3[1];
        float4 u4 = q4[0], v4 = q4[1];
        float4 u5 = q5[0], v5 = q5[1];
        float4 u6 = q6[0], v6 = q6[1];
        float4 u7 = q7[0], v7 = q7[1];
        add4(u0, u4); add4(v0, v4);
        add4(u1, u5); add4(v1, v5);
        add4(u2, u6); add4(v2, v6);
        add4(u3, u7); add4(v3, v7);
        add4(a0, u0); add4(b0, v0);
        add4(a1, u1); add4(b1, v1);
        add4(a2, u2); add4(b2, v2);
        add4(a3, u3); add4(b3, v3);
    }
    for (; e + 4 <= n; e += 4) {
        int4 ss = *(const int4*)&lst[e];
        const float4* p0 = (const float4*)&gsrc[(size_t)ss.x * HH + k0];
        const float4* p1 = (const float4*)&gsrc[(size_t)ss.y * HH + k0];
        const float4* p2 = (const float4*)&gsrc[(size_t)ss.z * HH + k0];
        const float4* p3 = (const float4*)&gsrc[(size_t)ss.w * HH + k0];
        float4 u0 = p0[0], v0 = p0[1];
        float4 u1 = p1[0], v1 = p1[1];
        float4 u2 = p2[0], v2 = p2[1];
        float4 u3 = p3[0], v3 = p3[1];
        add4(a0, u0); add4(b0, v0);
        add4(a1, u1); add4(b1, v1);
        add4(a2, u2); add4(b2, v2);
        add4(a3, u3); add4(b3, v3);
    }
    for (; e < n; ++e) {
        int s = lst[e];
        const float4* p0 = (const float4*)&gsrc[(size_t)s * HH + k0];
        float4 u0 = p0[0], v0 = p0[1];
        add4(a0, u0); add4(b0, v0);
    }
    add4(a0, a1); add4(b0, b1);
    add4(a2, a3); add4(b2, b3);
    add4(a0, a2); add4(b0, b2);
    float inv = 1.0f / fmaxf((float)ntru, 1.0f);
    a0.x *= inv; a0.y *= inv; a0.z *= inv; a0.w *= inv;
    b0.x *= inv; b0.y *= inv; b0.z *= inv; b0.w *= inv;
    int dst8 = (r * 16 + ((k0 >> 3) ^ (r & 7))) * 8;
    bf16x8 hi, lo;
    split8(a0, b0, hi, lo);
    *(bf16x8*)&lds[dst8] = hi;
    *(bf16x8*)&lds[4096 + dst8] = lo;
    split8(ha, hb, hi, lo);
    *(bf16x8*)&lds[8192 + dst8] = hi;
    *(bf16x8*)&lds[12288 + dst8] = lo;
}

// ========= PAIR kernel (M=32): sage2+gru(t_gru) ∥ sage layer-1(t_sage) =======
// 512 threads / 8 waves; wave wid owns jt = wid. Roles: [gru-C|sage-C|gru-P|sage-P].
__global__ __launch_bounds__(512, 2)
void pair_kernel(int bndGC, int bndSC, int bndGP,
                 const int* __restrict__ cntP_all, const int* __restrict__ cntC_all,
                 const int* __restrict__ listP_all, const int* __restrict__ listC_all,
                 const float* __restrict__ hp_all, const float* __restrict__ hc_all,
                 float* __restrict__ hp1A, float* __restrict__ hc1A,
                 float* __restrict__ hp1B, float* __restrict__ hc1B,
                 int t_gru, int t_sage,
                 const unsigned short* __restrict__ blob_s1cp, const float* __restrict__ bl1_cp,
                 const unsigned short* __restrict__ blob_s1pc, const float* __restrict__ bl1_pc,
                 const unsigned short* __restrict__ blob_s2cp, const float* __restrict__ bl2_cp,
                 const unsigned short* __restrict__ blob_s2pc, const float* __restrict__ bl2_pc,
                 const unsigned short* __restrict__ blob_gp,
                 const float* __restrict__ b_ih_p, const float* __restrict__ b_hh_p,
                 const unsigned short* __restrict__ blob_gc,
                 const float* __restrict__ b_ih_c, const float* __restrict__ b_hh_c,
                 float* __restrict__ h_c, float* __restrict__ h_p) {
    __shared__ unsigned short lds[4 * 4096];
    int bid = blockIdx.x;
    bool isGru, isC;
    int idx;
    if (bid < bndGC)      { isGru = true;  isC = true;  idx = bid; }
    else if (bid < bndSC) { isGru = false; isC = true;  idx = bid - bndGC; }
    else if (bid < bndGP) { isGru = true;  isC = false; idx = bid - bndSC; }
    else                  { isGru = false; isC = false; idx = bid - bndGP; }

    float* hp1_g = (t_gru & 1) ? hp1B : hp1A;
    float* hc1_g = (t_gru & 1) ? hc1B : hc1A;
    float* hp1_s = (t_sage & 1) ? hp1B : hp1A;
    float* hc1_s = (t_sage & 1) ? hc1B : hc1A;

    const int* cnt; const int* list; int CAP;
    const float* gsrc; const float* hin;
    const unsigned short* sblob; const float* sbl;
    const unsigned short* gblob; const float* bih; const float* bhh;
    float* outp;
    int N, i0 = idx * 32;
    if (isGru) {
        if (isC) {
            cnt = cntC_all + (size_t)t_gru * NCN;
            list = listC_all + (size_t)t_gru * NCN * CAPC; CAP = CAPC;
            gsrc = hp1_g; hin = hc1_g;
            sblob = blob_s2pc; sbl = bl2_pc;
            gblob = blob_gc; bih = b_ih_c; bhh = b_hh_c;
            outp = h_c; N = NCN;
        } else {
            cnt = cntP_all + (size_t)t_gru * NPN;
            list = listP_all + (size_t)t_gru * NPN * CAPP; CAP = CAPP;
            gsrc = hc1_g; hin = hp1_g;
            sblob = blob_s2cp; sbl = bl2_cp;
            gblob = blob_gp; bih = b_ih_p; bhh = b_hh_p;
            outp = h_p; N = NPN;
        }
    } else {
        const float* hp_t = hp_all + (size_t)t_sage * NPN * HH;
        const float* hc_t = hc_all + (size_t)t_sage * NCN * HH;
        if (isC) {
            cnt = cntC_all + (size_t)t_sage * NCN;
            list = listC_all + (size_t)t_sage * NCN * CAPC; CAP = CAPC;
            gsrc = hp_t; hin = hc_t;
            sblob = blob_s1pc; sbl = bl1_pc;
            gblob = nullptr; bih = nullptr; bhh = nullptr;
            outp = hc1_s; N = NCN;
        } else {
            cnt = cntP_all + (size_t)t_sage * NPN;
            list = listP_all + (size_t)t_sage * NPN * CAPP; CAP = CAPP;
            gsrc = hc_t; hin = hp_t;
            sblob = blob_s1cp; sbl = bl1_cp;
            gblob = nullptr; bih = nullptr; bhh = nullptr;
            outp = hp1_s; N = NPN;
        }
    }
    int tid = threadIdx.x;
    int wid = tid >> 6, lane = tid & 63;
    int jt = wid;
    int sr = tid >> 4, sk0 = (tid & 15) * 8;

    // ---- hprev preload (gru role) ------------------------------------------
    float4 hpre0, hpre1;
    if (isGru) {
        int row = i0 + sr; if (row >= N) row = N - 1;
        hpre0 = *(const float4*)&outp[(size_t)row * HH + sk0];
        hpre1 = *(const float4*)&outp[(size_t)row * HH + sk0 + 4];
    }

    stage512(lds, cnt, list, CAP, gsrc, hin, i0, N, tid);

    // ---- prefetch sage blob quad for kc=0 ----------------------------------
    bf16x8 sp0, sp1, sp2, sp3;
    {
        int nb = (jt * 4 + 0) * 2048 + lane * 8;
        sp0 = *(const bf16x8*)&sblob[nb];
        sp1 = *(const bf16x8*)&sblob[nb + 512];
        sp2 = *(const bf16x8*)&sblob[nb + 1024];
        sp3 = *(const bf16x8*)&sblob[nb + 1536];
    }
    __syncthreads();

    // ---- sage MFMA with B double-buffer ------------------------------------
    f32x4 acc[2];
    acc[0] = (f32x4){0.f, 0.f, 0.f, 0.f};
    acc[1] = (f32x4){0.f, 0.f, 0.f, 0.f};
#pragma unroll
    for (int kc = 0; kc < 4; ++kc) {
        bf16x8 c0 = sp0, c1 = sp1, c2 = sp2, c3 = sp3;
        if (kc < 3) {
            int nb = (jt * 4 + kc + 1) * 2048 + lane * 8;
            sp0 = *(const bf16x8*)&sblob[nb];
            sp1 = *(const bf16x8*)&sblob[nb + 512];
            sp2 = *(const bf16x8*)&sblob[nb + 1024];
            sp3 = *(const bf16x8*)&sblob[nb + 1536];
        }
#pragma unroll
        for (int mt = 0; mt < 2; ++mt) {
            int rl = mt * 16 + (lane & 15);
            int aoff = (rl * 16 + ((kc * 4 + (lane >> 4)) ^ (rl & 7))) * 8;
            bf16x8 amh = *(const bf16x8*)&lds[aoff];
            bf16x8 aml = *(const bf16x8*)&lds[4096 + aoff];
            bf16x8 ahh = *(const bf16x8*)&lds[8192 + aoff];
            bf16x8 ahl = *(const bf16x8*)&lds[12288 + aoff];
            acc[mt] = __builtin_amdgcn_mfma_f32_16x16x32_bf16(amh, c0, acc[mt], 0, 0, 0);
            acc[mt] = __builtin_amdgcn_mfma_f32_16x16x32_bf16(aml, c0, acc[mt], 0, 0, 0);
            acc[mt] = __builtin_amdgcn_mfma_f32_16x16x32_bf16(amh, c1, acc[mt], 0, 0, 0);
            acc[mt] = __builtin_amdgcn_mfma_f32_16x16x32_bf16(ahh, c2, acc[mt], 0, 0, 0);
            acc[mt] = __builtin_amdgcn_mfma_f32_16x16x32_bf16(ahl, c2, acc[mt], 0, 0, 0);
            acc[mt] = __builtin_amdgcn_mfma_f32_16x16x32_bf16(ahh, c3, acc[mt], 0, 0, 0);
        }
    }
    int j = jt * 16 + (lane & 15);

    if (!isGru) {
        float bv = sbl[j];
#pragma unroll
        for (int mt = 0; mt < 2; ++mt) {
#pragma unroll
            for (int q = 0; q < 4; ++q) {
                int r_loc = mt * 16 + (lane >> 4) * 4 + q;
                int row = i0 + r_loc;
                if (row >= N) continue;
                float v = fmaxf(acc[mt][q] + bv, 0.0f);
                outp[(size_t)row * HH + j] = v;
            }
        }
        return;
    }

    // ---- GRU phase C: x = acc + bias into LDS 0/1; hprev into 2/3 ----------
    __syncthreads();
    {
        float bv = sbl[j];
#pragma unroll
        for (int mt = 0; mt < 2; ++mt) {
#pragma unroll
            for (int q = 0; q < 4; ++q) {
                int r_loc = mt * 16 + (lane >> 4) * 4 + q;
                float v = acc[mt][q] + bv;
                unsigned short hi = f2bf(v);
                unsigned short lo = f2bf(v - bf2f(hi));
                int off = (r_loc * 16 + ((j >> 3) ^ (r_loc & 7))) * 8 + (j & 7);
                lds[off] = hi;
                lds[4096 + off] = lo;
            }
        }
        int dst8 = (sr * 16 + ((sk0 >> 3) ^ (sr & 7))) * 8;
        bf16x8 hi, lo;
        split8(hpre0, hpre1, hi, lo);
        *(bf16x8*)&lds[8192 + dst8] = hi;
        *(bf16x8*)&lds[12288 + dst8] = lo;
    }
    // prefetch first gru quad (kc=0, gate r)
    bf16x8 cq0, cq1, cq2, cq3;
    {
        int nb = (jt * 4 + 0) * 6144 + lane * 8;
        cq0 = *(const bf16x8*)&gblob[nb];
        cq1 = *(const bf16x8*)&gblob[nb + 512];
        cq2 = *(const bf16x8*)&gblob[nb + 1024];
        cq3 = *(const bf16x8*)&gblob[nb + 1536];
    }
    __syncthreads();

    // ---- GRU MFMA: (kc,gate) steps with one-quad lookahead -----------------
    f32x4 ar[2], az[2], an[2], ahn[2];
#pragma unroll
    for (int m = 0; m < 2; ++m) {
        ar[m] = (f32x4){0.f, 0.f, 0.f, 0.f};
        az[m] = (f32x4){0.f, 0.f, 0.f, 0.f};
        an[m] = (f32x4){0.f, 0.f, 0.f, 0.f};
        ahn[m] = (f32x4){0.f, 0.f, 0.f, 0.f};
    }
#pragma unroll
    for (int kc = 0; kc < 4; ++kc) {
        bf16x8 axh[2], axl[2], ahh[2], ahl[2];
#pragma unroll
        for (int mt = 0; mt < 2; ++mt) {
            int rl = mt * 16 + (lane & 15);
            int aoff = (rl * 16 + ((kc * 4 + (lane >> 4)) ^ (rl & 7))) * 8;
            axh[mt] = *(const bf16x8*)&lds[aoff];
            axl[mt] = *(const bf16x8*)&lds[4096 + aoff];
            ahh[mt] = *(const bf16x8*)&lds[8192 + aoff];
            ahl[mt] = *(const bf16x8*)&lds[12288 + aoff];
        }
        int bbase = (jt * 4 + kc) * 6144 + lane * 8;
#pragma unroll
        for (int g = 0; g < 3; ++g) {
            bf16x8 nq0, nq1, nq2, nq3;
            if (!(kc == 3 && g == 2)) {
                int nb = (g < 2) ? (bbase + (g + 1) * 2048)
                                 : ((jt * 4 + kc + 1) * 6144 + lane * 8);
                nq0 = *(const bf16x8*)&gblob[nb];
                nq1 = *(const bf16x8*)&gblob[nb + 512];
                nq2 = *(const bf16x8*)&gblob[nb + 1024];
                nq3 = *(const bf16x8*)&gblob[nb + 1536];
            }
#pragma unroll
            for (int mt = 0; mt < 2; ++mt) {
                if (g == 2) {
                    an[mt] = __builtin_amdgcn_mfma_f32_16x16x32_bf16(axh[mt], cq0, an[mt], 0, 0, 0);
                    an[mt] = __builtin_amdgcn_mfma_f32_16x16x32_bf16(axl[mt], cq0, an[mt], 0, 0, 0);
                    an[mt] = __builtin_amdgcn_mfma_f32_16x16x32_bf16(axh[mt], cq1, an[mt], 0, 0, 0);
                    ahn[mt] = __builtin_amdgcn_mfma_f32_16x16x32_bf16(ahh[mt], cq2, ahn[mt], 0, 0, 0);
                    ahn[mt] = __builtin_amdgcn_mfma_f32_16x16x32_bf16(ahl[mt], cq2, ahn[mt], 0, 0, 0);
                    ahn[mt] = __builtin_amdgcn_mfma_f32_16x16x32_bf16(ahh[mt], cq3, ahn[mt], 0, 0, 0);
                } else {
                    f32x4& a = (g == 0) ? ar[mt] : az[mt];
                    a = __builtin_amdgcn_mfma_f32_16x16x32_bf16(axh[mt], cq0, a, 0, 0, 0);
                    a = __builtin_amdgcn_mfma_f32_16x16x32_bf16(axl[mt], cq0, a, 0, 0, 0);
                    a = __builtin_amdgcn_mfma_f32_16x16x32_bf16(axh[mt], cq1, a, 0, 0, 0);
                    a = __builtin_amdgcn_mfma_f32_16x16x32_bf16(ahh[mt], cq2, a, 0, 0, 0);
                    a = __builtin_amdgcn_mfma_f32_16x16x32_bf16(ahl[mt], cq2, a, 0, 0, 0);
                    a = __builtin_amdgcn_mfma_f32_16x16x32_bf16(ahh[mt], cq3, a, 0, 0, 0);
                }
            }
            if (!(kc == 3 && g == 2)) {
                cq0 = nq0; cq1 = nq1; cq2 = nq2; cq3 = nq3;
            }
        }
    }
    {
        float br = bih[j] + bhh[j];
        float bz = bih[HH + j] + bhh[HH + j];
        float bn_i = bih[2 * HH + j];
        float bn_h = bhh[2 * HH + j];
#pragma unroll
        for (int mt = 0; mt < 2; ++mt) {
#pragma unroll
            for (int q = 0; q < 4; ++q) {
                int r_loc = mt * 16 + (lane >> 4) * 4 + q;
                int row = i0 + r_loc;
                if (row >= N) continue;
                float pr = ar[mt][q] + br;
                float pz = az[mt][q] + bz;
                float pn = an[mt][q] + bn_i;
                float phn = ahn[mt][q] + bn_h;
                float rg = 1.0f / (1.0f + __expf(-pr));
                float zg = 1.0f / (1.0f + __expf(-pz));
                float ng = tanhf(pn + rg * phn);
                int eo = (r_loc * 16 + ((j >> 3) ^ (r_loc & 7))) * 8 + (j & 7);
                float hprev = bf2f(lds[8192 + eo]) + bf2f(lds[12288 + eo]);
                outp[(size_t)row * HH + j] = (1.0f - zg) * ng + zg * hprev;
            }
        }
    }
}

extern "C" void kernel_launch(void* const* d_in, const int* in_sizes, int n_in,
                              void* d_out, int out_size, void* d_ws, size_t ws_size,
                              hipStream_t stream) {
    const float* xc     = (const float*)d_in[0];
    const float* xp     = (const float*)d_in[1];
    const int*   esrc   = (const int*)d_in[2];
    const int*   edst   = (const int*)d_in[3];
    const float* w_clin = (const float*)d_in[4];
    const float* b_clin = (const float*)d_in[5];
    const float* w_plin = (const float*)d_in[6];
    const float* b_plin = (const float*)d_in[7];
    const float* wl1_cp = (const float*)d_in[8];
    const float* wr1_cp = (const float*)d_in[9];
    const float* wl1_pc = (const float*)d_in[10];
    const float* wr1_pc = (const float*)d_in[11];
    const float* wl2_cp = (const float*)d_in[12];
    const float* wr2_cp = (const float*)d_in[13];
    const float* wl2_pc = (const float*)d_in[14];
    const float* wr2_pc = (const float*)d_in[15];
    const float* bl1_cp = (const float*)d_in[16];
    const float* bl1_pc = (const float*)d_in[17];
    const float* bl2_cp = (const float*)d_in[18];
    const float* bl2_pc = (const float*)d_in[19];
    const float* w_ih_c = (const float*)d_in[20];
    const float* w_hh_c = (const float*)d_in[21];
    const float* w_ih_p = (const float*)d_in[22];
    const float* w_hh_p = (const float*)d_in[23];
    const float* b_ih_c = (const float*)d_in[24];
    const float* b_hh_c = (const float*)d_in[25];
    const float* b_ih_p = (const float*)d_in[26];
    const float* b_hh_p = (const float*)d_in[27];

    float* ws      = (float*)d_ws;
    float* hp_all  = ws;
    float* hc_all  = hp_all + (size_t)TT * NPN * HH;
    float* hp1A    = hc_all + (size_t)TT * NCN * HH;
    float* hc1A    = hp1A + (size_t)NPN * HH;
    float* hp1B    = hc1A + (size_t)NCN * HH;
    float* hc1B    = hp1B + (size_t)NPN * HH;
    int*   cntP_all = (int*)(hc1B + (size_t)NCN * HH);
    int*   cntC_all = cntP_all + (size_t)TT * NPN;
    int*   listP_all = cntC_all + (size_t)TT * NCN;
    int*   listC_all = listP_all + (size_t)TT * NPN * CAPP;

    unsigned short* fw = (unsigned short*)(listC_all + (size_t)TT * NCN * CAPC);
    const int SB = 65536;
    const int GB = 196608;
    unsigned short* blob_s1cp = fw;
    unsigned short* blob_s1pc = blob_s1cp + SB;
    unsigned short* blob_s2cp = blob_s1pc + SB;
    unsigned short* blob_s2pc = blob_s2cp + SB;
    unsigned short* blob_gp   = blob_s2pc + SB;
    unsigned short* blob_gc   = blob_gp + GB;
    unsigned short* blob_lc   = blob_gc + GB;
    unsigned short* blob_lp   = blob_lc + 8192;

    float* h_c = (float*)d_out;
    float* h_p = h_c + (size_t)NCN * HH;

    {
        const int B = 256;
        int gs = (HH * HH + B - 1) / B;
        sage_wprep<<<gs, B, 0, stream>>>(wl1_cp, wr1_cp, blob_s1cp);
        sage_wprep<<<gs, B, 0, stream>>>(wl1_pc, wr1_pc, blob_s1pc);
        sage_wprep<<<gs, B, 0, stream>>>(wl2_cp, wr2_cp, blob_s2cp);
        sage_wprep<<<gs, B, 0, stream>>>(wl2_pc, wr2_pc, blob_s2pc);
        int gg = (3 * HH * HH + B - 1) / B;
        gru_wprep<<<gg, B, 0, stream>>>(w_ih_p, w_hh_p, blob_gp);
        gru_wprep<<<gg, B, 0, stream>>>(w_ih_c, w_hh_c, blob_gc);
        lin_wprep<<<(HH * 32 + B - 1) / B, B, 0, stream>>>(w_clin, blob_lc, 32);
        lin_wprep<<<(HH * 64 + B - 1) / B, B, 0, stream>>>(w_plin, blob_lp, 64);
    }

    hipMemsetAsync(d_out, 0, (size_t)out_size * sizeof(float), stream);
    hipMemsetAsync(cntP_all, 0, (size_t)TT * (NPN + NCN) * sizeof(int), stream);

    build_kernel<<<(TT * EE + 255) / 256, 256, 0, stream>>>(esrc, edst, cntP_all, cntC_all,
                                                            listP_all, listC_all);
    linproj_mfma<32><<<(TT * NCN + 31) / 32, 256, 0, stream>>>(xc, blob_lc, b_clin, hc_all, TT * NCN);
    linproj_mfma<64><<<(TT * NPN + 31) / 32, 256, 0, stream>>>(xp, blob_lp, b_plin, hp_all, TT * NPN);

    const int gP32 = (NPN + 31) / 32, gC32 = (NCN + 31) / 32;

    for (int k = 0; k <= TT; ++k) {
        int hasG = (k >= 1), hasS = (k < TT);
        int t_g = hasG ? (k - 1) : 0;
        int t_s = hasS ? k : 0;
        int bndGC = hasG ? gC32 : 0;
        int bndSC = bndGC + (hasS ? gC32 : 0);
        int bndGP = bndSC + (hasG ? gP32 : 0);
        int grid  = bndGP + (hasS ? gP32 : 0);
        pair_kernel<<<grid, 512, 0, stream>>>(
            bndGC, bndSC, bndGP,
            cntP_all, cntC_all, listP_all, listC_all,
            hp_all, hc_all, hp1A, hc1A, hp1B, hc1B,
            t_g, t_s,
            blob_s1cp, bl1_cp, blob_s1pc, bl1_pc,
            blob_s2cp, bl2_cp, blob_s2pc, bl2_pc,
            blob_gp, b_ih_p, b_hh_p,
            blob_gc, b_ih_c, b_hh_c,
            h_c, h_p);
    }
}

// Round 19
// 690.501 us; speedup vs baseline: 1.1418x; 1.1065x over previous
//
#include <hip/hip_runtime.h>

#define NCN 3000
#define NPN 30000
#define TT 8
#define EE 64000
#define HH 128
#define CAPP 24
#define CAPC 64

typedef __attribute__((ext_vector_type(8))) short bf16x8;
typedef __attribute__((ext_vector_type(4))) float f32x4;

__device__ inline unsigned short f2bf(float f) {
    unsigned u = __float_as_uint(f);
    u += 0x7FFF + ((u >> 16) & 1);
    return (unsigned short)(u >> 16);
}
__device__ inline float bf2f(unsigned short h) {
    return __uint_as_float(((unsigned)h) << 16);
}
__device__ inline void split8(const float4 a, const float4 b, bf16x8& hi, bf16x8& lo) {
    float v[8] = {a.x, a.y, a.z, a.w, b.x, b.y, b.z, b.w};
#pragma unroll
    for (int i = 0; i < 8; ++i) {
        unsigned short hs = f2bf(v[i]);
        float rem = v[i] - bf2f(hs);
        hi[i] = (short)hs;
        lo[i] = (short)f2bf(rem);
    }
}
__device__ inline void add4(float4& a, const float4 b) {
    a.x += b.x; a.y += b.y; a.z += b.z; a.w += b.w;
}

// ---- linproj weight pack ----------------------------------------------------
__global__ void lin_wprep(const float* __restrict__ w, unsigned short* __restrict__ blob,
                          int K) {
    int idx = blockIdx.x * blockDim.x + threadIdx.x;
    if (idx >= HH * K) return;
    int n = idx / K, k = idx - n * K;
    int nt = n >> 4, nl = n & 15;
    int kc = k >> 5, kg = (k >> 3) & 3, kj = k & 7;
    int KC = K >> 5;
    int base = (nt * KC + kc) * 1024 + (kg * 16 + nl) * 8 + kj;
    float f = w[idx];
    unsigned short hi = f2bf(f), lo = f2bf(f - bf2f(hi));
    blob[base] = hi;
    blob[base + 512] = lo;
}

// ---- SAGE weight pack -------------------------------------------------------
__global__ void sage_wprep(const float* __restrict__ wl, const float* __restrict__ wr,
                           unsigned short* __restrict__ blob) {
    int idx = blockIdx.x * blockDim.x + threadIdx.x;
    if (idx >= HH * HH) return;
    int n = idx >> 7, k = idx & 127;
    int jt = n >> 4, nl = n & 15;
    int kc = k >> 5, kg = (k >> 3) & 3, kj = k & 7;
    int base = (jt * 4 + kc) * 2048 + (kg * 16 + nl) * 8 + kj;
    float f = wl[idx];
    unsigned short hi = f2bf(f), lo = f2bf(f - bf2f(hi));
    blob[base] = hi;
    blob[base + 512] = lo;
    f = wr[idx];
    hi = f2bf(f); lo = f2bf(f - bf2f(hi));
    blob[base + 1024] = hi;
    blob[base + 1536] = lo;
}

// ---- GRU weight pack ---------------------------------------------------------
__global__ void gru_wprep(const float* __restrict__ wih, const float* __restrict__ whh,
                          unsigned short* __restrict__ blob) {
    int idx = blockIdx.x * blockDim.x + threadIdx.x;
    if (idx >= 3 * HH * HH) return;
    int n = idx >> 7, k = idx & 127;
    int gate = n >> 7, j128 = n & 127;
    int jt = j128 >> 4, nl = j128 & 15;
    int kc = k >> 5, kg = (k >> 3) & 3, kj = k & 7;
    int base = (jt * 4 + kc) * 6144 + gate * 2048 + (kg * 16 + nl) * 8 + kj;
    float f = wih[idx];
    unsigned short hi = f2bf(f), lo = f2bf(f - bf2f(hi));
    blob[base] = hi;
    blob[base + 512] = lo;
    f = whh[idx];
    hi = f2bf(f); lo = f2bf(f - bf2f(hi));
    blob[base + 1024] = hi;
    blob[base + 1536] = lo;
}

// ---------------- input projection via split-bf16 MFMA -----------------------
template<int K>
__global__ __launch_bounds__(256, 4)
void linproj_mfma(const float* __restrict__ x, const unsigned short* __restrict__ blob,
                  const float* __restrict__ b, float* __restrict__ out, int N) {
    const int SLOTS = K / 8;
    const int KC = K / 32;
    __shared__ unsigned short lds[2 * 32 * K];
    int i0 = blockIdx.x * 32;
    int tid = threadIdx.x;
    if (tid * 8 < 32 * K) {
        int linear = tid * 8;
        int r = linear / K, k0 = linear % K;
        int row = i0 + r; if (row >= N) row = N - 1;
        float4 a = *(const float4*)&x[(size_t)row * K + k0];
        float4 b4 = *(const float4*)&x[(size_t)row * K + k0 + 4];
        bf16x8 hi, lo;
        split8(a, b4, hi, lo);
        int dst8 = (r * SLOTS + ((k0 >> 3) ^ (r & (SLOTS - 1)))) * 8;
        *(bf16x8*)&lds[dst8] = hi;
        *(bf16x8*)&lds[32 * K + dst8] = lo;
    }
    __syncthreads();
    int wid = tid >> 6, lane = tid & 63;
    int jt0 = wid * 2;
    f32x4 acc[2][2];
#pragma unroll
    for (int a = 0; a < 2; ++a)
#pragma unroll
        for (int m = 0; m < 2; ++m) acc[a][m] = (f32x4){0.f, 0.f, 0.f, 0.f};
#pragma unroll
    for (int kc = 0; kc < KC; ++kc) {
        bf16x8 ah[2], al[2];
#pragma unroll
        for (int mt = 0; mt < 2; ++mt) {
            int rl = mt * 16 + (lane & 15);
            int slot = (kc * 4 + (lane >> 4)) ^ (rl & (SLOTS - 1));
            int aoff = (rl * SLOTS + slot) * 8;
            ah[mt] = *(const bf16x8*)&lds[aoff];
            al[mt] = *(const bf16x8*)&lds[32 * K + aoff];
        }
#pragma unroll
        for (int jj = 0; jj < 2; ++jj) {
            int bbase = ((jt0 + jj) * KC + kc) * 1024 + lane * 8;
            bf16x8 f0 = *(const bf16x8*)&blob[bbase];
            bf16x8 f1 = *(const bf16x8*)&blob[bbase + 512];
#pragma unroll
            for (int mt = 0; mt < 2; ++mt) {
                acc[jj][mt] = __builtin_amdgcn_mfma_f32_16x16x32_bf16(ah[mt], f0, acc[jj][mt], 0, 0, 0);
                acc[jj][mt] = __builtin_amdgcn_mfma_f32_16x16x32_bf16(al[mt], f0, acc[jj][mt], 0, 0, 0);
                acc[jj][mt] = __builtin_amdgcn_mfma_f32_16x16x32_bf16(ah[mt], f1, acc[jj][mt], 0, 0, 0);
            }
        }
    }
#pragma unroll
    for (int jj = 0; jj < 2; ++jj) {
        int j = (jt0 + jj) * 16 + (lane & 15);
        float bv = b[j];
#pragma unroll
        for (int mt = 0; mt < 2; ++mt) {
#pragma unroll
            for (int q = 0; q < 4; ++q) {
                int r_loc = mt * 16 + (lane >> 4) * 4 + q;
                int row = i0 + r_loc;
                if (row < N) out[(size_t)row * HH + j] = acc[jj][mt][q] + bv;
            }
        }
    }
}

// ---------------- edge bucket build, all timesteps ---------------------------
__global__ void build_kernel(const int* __restrict__ es, const int* __restrict__ ed,
                             int* __restrict__ cntP, int* __restrict__ cntC,
                             int* __restrict__ listP, int* __restrict__ listC) {
    int g = blockIdx.x * 256 + threadIdx.x;
    if (g >= TT * EE) return;
    int t = g / EE;
    int s = es[g], d = ed[g];
    int pP = atomicAdd(&cntP[t * NPN + d], 1);
    if (pP < CAPP) listP[((size_t)t * NPN + d) * CAPP + pP] = s;
    int pC = atomicAdd(&cntC[t * NCN + s], 1);
    if (pC < CAPC) listC[((size_t)t * NCN + s) * CAPC + pC] = d;
}

// ---- staging M=64, 1024 threads: one (row, 8-col slice) per thread ----------
// LDS regions (ushort units): msg_hi 0, msg_lo 8192, self_hi 16384, self_lo 24576
__device__ inline void stage1024(unsigned short* lds, const int* cnt, const int* list,
                                 int CAP, const float* gsrc, const float* hin,
                                 int i0, int N, int tid) {
    int r = tid >> 4, k0 = (tid & 15) * 8;
    int row = i0 + r; if (row >= N) row = N - 1;
    float4 ha = *(const float4*)&hin[(size_t)row * HH + k0];
    float4 hb = *(const float4*)&hin[(size_t)row * HH + k0 + 4];
    int ntru = cnt[row];
    int n = ntru > CAP ? CAP : ntru;
    const int* lst = &list[(size_t)row * CAP];
    float4 a0 = {0,0,0,0}, b0 = {0,0,0,0}, a1 = {0,0,0,0}, b1 = {0,0,0,0};
    float4 a2 = {0,0,0,0}, b2 = {0,0,0,0}, a3 = {0,0,0,0}, b3 = {0,0,0,0};
    int e = 0;
    for (; e + 4 <= n; e += 4) {
        int4 ss = *(const int4*)&lst[e];
        const float4* p0 = (const float4*)&gsrc[(size_t)ss.x * HH + k0];
        const float4* p1 = (const float4*)&gsrc[(size_t)ss.y * HH + k0];
        const float4* p2 = (const float4*)&gsrc[(size_t)ss.z * HH + k0];
        const float4* p3 = (const float4*)&gsrc[(size_t)ss.w * HH + k0];
        float4 u0 = p0[0], v0 = p0[1];
        float4 u1 = p1[0], v1 = p1[1];
        float4 u2 = p2[0], v2 = p2[1];
        float4 u3 = p3[0], v3 = p3[1];
        add4(a0, u0); add4(b0, v0);
        add4(a1, u1); add4(b1, v1);
        add4(a2, u2); add4(b2, v2);
        add4(a3, u3); add4(b3, v3);
    }
    for (; e < n; ++e) {
        int s = lst[e];
        const float4* p0 = (const float4*)&gsrc[(size_t)s * HH + k0];
        float4 u0 = p0[0], v0 = p0[1];
        add4(a0, u0); add4(b0, v0);
    }
    add4(a0, a1); add4(b0, b1);
    add4(a2, a3); add4(b2, b3);
    add4(a0, a2); add4(b0, b2);
    float inv = 1.0f / fmaxf((float)ntru, 1.0f);
    a0.x *= inv; a0.y *= inv; a0.z *= inv; a0.w *= inv;
    b0.x *= inv; b0.y *= inv; b0.z *= inv; b0.w *= inv;
    int dst8 = (r * 16 + ((k0 >> 3) ^ (r & 7))) * 8;
    bf16x8 hi, lo;
    split8(a0, b0, hi, lo);
    *(bf16x8*)&lds[dst8] = hi;
    *(bf16x8*)&lds[8192 + dst8] = lo;
    split8(ha, hb, hi, lo);
    *(bf16x8*)&lds[16384 + dst8] = hi;
    *(bf16x8*)&lds[24576 + dst8] = lo;
}

// ========= PAIR kernel (M=64, 1024 thr / 16 waves) ===========================
// wave wid: jt = wid&7, m-half mh = wid>>3 -> m-tiles {mh*2, mh*2+1}.
__global__ __launch_bounds__(1024, 4)
void pair_kernel(int bndGC, int bndSC, int bndGP,
                 const int* __restrict__ cntP_all, const int* __restrict__ cntC_all,
                 const int* __restrict__ listP_all, const int* __restrict__ listC_all,
                 const float* __restrict__ hp_all, const float* __restrict__ hc_all,
                 float* __restrict__ hp1A, float* __restrict__ hc1A,
                 float* __restrict__ hp1B, float* __restrict__ hc1B,
                 int t_gru, int t_sage,
                 const unsigned short* __restrict__ blob_s1cp, const float* __restrict__ bl1_cp,
                 const unsigned short* __restrict__ blob_s1pc, const float* __restrict__ bl1_pc,
                 const unsigned short* __restrict__ blob_s2cp, const float* __restrict__ bl2_cp,
                 const unsigned short* __restrict__ blob_s2pc, const float* __restrict__ bl2_pc,
                 const unsigned short* __restrict__ blob_gp,
                 const float* __restrict__ b_ih_p, const float* __restrict__ b_hh_p,
                 const unsigned short* __restrict__ blob_gc,
                 const float* __restrict__ b_ih_c, const float* __restrict__ b_hh_c,
                 float* __restrict__ h_c, float* __restrict__ h_p) {
    __shared__ unsigned short lds[4 * 8192];   // 64 KB
    int bid = blockIdx.x;
    bool isGru, isC;
    int idx;
    if (bid < bndGC)      { isGru = true;  isC = true;  idx = bid; }
    else if (bid < bndSC) { isGru = false; isC = true;  idx = bid - bndGC; }
    else if (bid < bndGP) { isGru = true;  isC = false; idx = bid - bndSC; }
    else                  { isGru = false; isC = false; idx = bid - bndGP; }

    float* hp1_g = (t_gru & 1) ? hp1B : hp1A;
    float* hc1_g = (t_gru & 1) ? hc1B : hc1A;
    float* hp1_s = (t_sage & 1) ? hp1B : hp1A;
    float* hc1_s = (t_sage & 1) ? hc1B : hc1A;

    const int* cnt; const int* list; int CAP;
    const float* gsrc; const float* hin;
    const unsigned short* sblob; const float* sbl;
    const unsigned short* gblob; const float* bih; const float* bhh;
    float* outp;
    int N, i0 = idx * 64;
    if (isGru) {
        if (isC) {
            cnt = cntC_all + (size_t)t_gru * NCN;
            list = listC_all + (size_t)t_gru * NCN * CAPC; CAP = CAPC;
            gsrc = hp1_g; hin = hc1_g;
            sblob = blob_s2pc; sbl = bl2_pc;
            gblob = blob_gc; bih = b_ih_c; bhh = b_hh_c;
            outp = h_c; N = NCN;
        } else {
            cnt = cntP_all + (size_t)t_gru * NPN;
            list = listP_all + (size_t)t_gru * NPN * CAPP; CAP = CAPP;
            gsrc = hc1_g; hin = hp1_g;
            sblob = blob_s2cp; sbl = bl2_cp;
            gblob = blob_gp; bih = b_ih_p; bhh = b_hh_p;
            outp = h_p; N = NPN;
        }
    } else {
        const float* hp_t = hp_all + (size_t)t_sage * NPN * HH;
        const float* hc_t = hc_all + (size_t)t_sage * NCN * HH;
        if (isC) {
            cnt = cntC_all + (size_t)t_sage * NCN;
            list = listC_all + (size_t)t_sage * NCN * CAPC; CAP = CAPC;
            gsrc = hp_t; hin = hc_t;
            sblob = blob_s1pc; sbl = bl1_pc;
            gblob = nullptr; bih = nullptr; bhh = nullptr;
            outp = hc1_s; N = NCN;
        } else {
            cnt = cntP_all + (size_t)t_sage * NPN;
            list = listP_all + (size_t)t_sage * NPN * CAPP; CAP = CAPP;
            gsrc = hc_t; hin = hp_t;
            sblob = blob_s1cp; sbl = bl1_cp;
            gblob = nullptr; bih = nullptr; bhh = nullptr;
            outp = hp1_s; N = NPN;
        }
    }
    int tid = threadIdx.x;
    int wid = tid >> 6, lane = tid & 63;
    int jt = wid & 7, mh = wid >> 3;   // m-tiles mh*2, mh*2+1
    int sr = tid >> 4, sk0 = (tid & 15) * 8;

    // ---- hprev preload (gru role) ------------------------------------------
    float4 hpre0, hpre1;
    if (isGru) {
        int row = i0 + sr; if (row >= N) row = N - 1;
        hpre0 = *(const float4*)&outp[(size_t)row * HH + sk0];
        hpre1 = *(const float4*)&outp[(size_t)row * HH + sk0 + 4];
    }

    stage1024(lds, cnt, list, CAP, gsrc, hin, i0, N, tid);
    __syncthreads();

    // ---- sage MFMA: wave owns (jt, 2 m-tiles) -------------------------------
    f32x4 acc[2];
    acc[0] = (f32x4){0.f, 0.f, 0.f, 0.f};
    acc[1] = (f32x4){0.f, 0.f, 0.f, 0.f};
#pragma unroll
    for (int kc = 0; kc < 4; ++kc) {
        int bbase = (jt * 4 + kc) * 2048 + lane * 8;
        bf16x8 c0 = *(const bf16x8*)&sblob[bbase];
        bf16x8 c1 = *(const bf16x8*)&sblob[bbase + 512];
        bf16x8 c2 = *(const bf16x8*)&sblob[bbase + 1024];
        bf16x8 c3 = *(const bf16x8*)&sblob[bbase + 1536];
#pragma unroll
        for (int mt = 0; mt < 2; ++mt) {
            int rl = (mh * 2 + mt) * 16 + (lane & 15);
            int aoff = (rl * 16 + ((kc * 4 + (lane >> 4)) ^ (rl & 7))) * 8;
            bf16x8 amh = *(const bf16x8*)&lds[aoff];
            bf16x8 aml = *(const bf16x8*)&lds[8192 + aoff];
            bf16x8 ahh = *(const bf16x8*)&lds[16384 + aoff];
            bf16x8 ahl = *(const bf16x8*)&lds[24576 + aoff];
            acc[mt] = __builtin_amdgcn_mfma_f32_16x16x32_bf16(amh, c0, acc[mt], 0, 0, 0);
            acc[mt] = __builtin_amdgcn_mfma_f32_16x16x32_bf16(aml, c0, acc[mt], 0, 0, 0);
            acc[mt] = __builtin_amdgcn_mfma_f32_16x16x32_bf16(amh, c1, acc[mt], 0, 0, 0);
            acc[mt] = __builtin_amdgcn_mfma_f32_16x16x32_bf16(ahh, c2, acc[mt], 0, 0, 0);
            acc[mt] = __builtin_amdgcn_mfma_f32_16x16x32_bf16(ahl, c2, acc[mt], 0, 0, 0);
            acc[mt] = __builtin_amdgcn_mfma_f32_16x16x32_bf16(ahh, c3, acc[mt], 0, 0, 0);
        }
    }
    int j = jt * 16 + (lane & 15);

    if (!isGru) {
        float bv = sbl[j];
#pragma unroll
        for (int mt = 0; mt < 2; ++mt) {
#pragma unroll
            for (int q = 0; q < 4; ++q) {
                int r_loc = (mh * 2 + mt) * 16 + (lane >> 4) * 4 + q;
                int row = i0 + r_loc;
                if (row >= N) continue;
                float v = fmaxf(acc[mt][q] + bv, 0.0f);
                outp[(size_t)row * HH + j] = v;
            }
        }
        return;
    }

    // ---- GRU phase C: x = acc + bias into regions 0/1; hprev into 2/3 ------
    __syncthreads();
    {
        float bv = sbl[j];
#pragma unroll
        for (int mt = 0; mt < 2; ++mt) {
#pragma unroll
            for (int q = 0; q < 4; ++q) {
                int r_loc = (mh * 2 + mt) * 16 + (lane >> 4) * 4 + q;
                float v = acc[mt][q] + bv;
                unsigned short hi = f2bf(v);
                unsigned short lo = f2bf(v - bf2f(hi));
                int off = (r_loc * 16 + ((j >> 3) ^ (r_loc & 7))) * 8 + (j & 7);
                lds[off] = hi;
                lds[8192 + off] = lo;
            }
        }
        int dst8 = (sr * 16 + ((sk0 >> 3) ^ (sr & 7))) * 8;
        bf16x8 hi, lo;
        split8(hpre0, hpre1, hi, lo);
        *(bf16x8*)&lds[16384 + dst8] = hi;
        *(bf16x8*)&lds[24576 + dst8] = lo;
    }
    __syncthreads();

    // ---- GRU MFMA: per kc load 12 B-frags; 2 m-tiles ------------------------
    f32x4 ar[2], az[2], an[2], ahn[2];
#pragma unroll
    for (int m = 0; m < 2; ++m) {
        ar[m] = (f32x4){0.f, 0.f, 0.f, 0.f};
        az[m] = (f32x4){0.f, 0.f, 0.f, 0.f};
        an[m] = (f32x4){0.f, 0.f, 0.f, 0.f};
        ahn[m] = (f32x4){0.f, 0.f, 0.f, 0.f};
    }
#pragma unroll
    for (int kc = 0; kc < 4; ++kc) {
        int bbase = (jt * 4 + kc) * 6144 + lane * 8;
        bf16x8 r0 = *(const bf16x8*)&gblob[bbase];
        bf16x8 r1 = *(const bf16x8*)&gblob[bbase + 512];
        bf16x8 r2 = *(const bf16x8*)&gblob[bbase + 1024];
        bf16x8 r3 = *(const bf16x8*)&gblob[bbase + 1536];
        bf16x8 z0 = *(const bf16x8*)&gblob[bbase + 2048];
        bf16x8 z1 = *(const bf16x8*)&gblob[bbase + 2560];
        bf16x8 z2 = *(const bf16x8*)&gblob[bbase + 3072];
        bf16x8 z3 = *(const bf16x8*)&gblob[bbase + 3584];
        bf16x8 n0 = *(const bf16x8*)&gblob[bbase + 4096];
        bf16x8 n1 = *(const bf16x8*)&gblob[bbase + 4608];
        bf16x8 n2 = *(const bf16x8*)&gblob[bbase + 5120];
        bf16x8 n3 = *(const bf16x8*)&gblob[bbase + 5632];
#pragma unroll
        for (int mt = 0; mt < 2; ++mt) {
            int rl = (mh * 2 + mt) * 16 + (lane & 15);
            int aoff = (rl * 16 + ((kc * 4 + (lane >> 4)) ^ (rl & 7))) * 8;
            bf16x8 axh = *(const bf16x8*)&lds[aoff];
            bf16x8 axl = *(const bf16x8*)&lds[8192 + aoff];
            bf16x8 ahh = *(const bf16x8*)&lds[16384 + aoff];
            bf16x8 ahl = *(const bf16x8*)&lds[24576 + aoff];
            ar[mt] = __builtin_amdgcn_mfma_f32_16x16x32_bf16(axh, r0, ar[mt], 0, 0, 0);
            ar[mt] = __builtin_amdgcn_mfma_f32_16x16x32_bf16(axl, r0, ar[mt], 0, 0, 0);
            ar[mt] = __builtin_amdgcn_mfma_f32_16x16x32_bf16(axh, r1, ar[mt], 0, 0, 0);
            ar[mt] = __builtin_amdgcn_mfma_f32_16x16x32_bf16(ahh, r2, ar[mt], 0, 0, 0);
            ar[mt] = __builtin_amdgcn_mfma_f32_16x16x32_bf16(ahl, r2, ar[mt], 0, 0, 0);
            ar[mt] = __builtin_amdgcn_mfma_f32_16x16x32_bf16(ahh, r3, ar[mt], 0, 0, 0);
            az[mt] = __builtin_amdgcn_mfma_f32_16x16x32_bf16(axh, z0, az[mt], 0, 0, 0);
            az[mt] = __builtin_amdgcn_mfma_f32_16x16x32_bf16(axl, z0, az[mt], 0, 0, 0);
            az[mt] = __builtin_amdgcn_mfma_f32_16x16x32_bf16(axh, z1, az[mt], 0, 0, 0);
            az[mt] = __builtin_amdgcn_mfma_f32_16x16x32_bf16(ahh, z2, az[mt], 0, 0, 0);
            az[mt] = __builtin_amdgcn_mfma_f32_16x16x32_bf16(ahl, z2, az[mt], 0, 0, 0);
            az[mt] = __builtin_amdgcn_mfma_f32_16x16x32_bf16(ahh, z3, az[mt], 0, 0, 0);
            an[mt] = __builtin_amdgcn_mfma_f32_16x16x32_bf16(axh, n0, an[mt], 0, 0, 0);
            an[mt] = __builtin_amdgcn_mfma_f32_16x16x32_bf16(axl, n0, an[mt], 0, 0, 0);
            an[mt] = __builtin_amdgcn_mfma_f32_16x16x32_bf16(axh, n1, an[mt], 0, 0, 0);
            ahn[mt] = __builtin_amdgcn_mfma_f32_16x16x32_bf16(ahh, n2, ahn[mt], 0, 0, 0);
            ahn[mt] = __builtin_amdgcn_mfma_f32_16x16x32_bf16(ahl, n2, ahn[mt], 0, 0, 0);
            ahn[mt] = __builtin_amdgcn_mfma_f32_16x16x32_bf16(ahh, n3, ahn[mt], 0, 0, 0);
        }
    }
    {
        float br = bih[j] + bhh[j];
        float bz = bih[HH + j] + bhh[HH + j];
        float bn_i = bih[2 * HH + j];
        float bn_h = bhh[2 * HH + j];
#pragma unroll
        for (int mt = 0; mt < 2; ++mt) {
#pragma unroll
            for (int q = 0; q < 4; ++q) {
                int r_loc = (mh * 2 + mt) * 16 + (lane >> 4) * 4 + q;
                int row = i0 + r_loc;
                if (row >= N) continue;
                float pr = ar[mt][q] + br;
                float pz = az[mt][q] + bz;
                float pn = an[mt][q] + bn_i;
                float phn = ahn[mt][q] + bn_h;
                float rg = 1.0f / (1.0f + __expf(-pr));
                float zg = 1.0f / (1.0f + __expf(-pz));
                float ng = tanhf(pn + rg * phn);
                int eo = (r_loc * 16 + ((j >> 3) ^ (r_loc & 7))) * 8 + (j & 7);
                float hprev = bf2f(lds[16384 + eo]) + bf2f(lds[24576 + eo]);
                outp[(size_t)row * HH + j] = (1.0f - zg) * ng + zg * hprev;
            }
        }
    }
}

extern "C" void kernel_launch(void* const* d_in, const int* in_sizes, int n_in,
                              void* d_out, int out_size, void* d_ws, size_t ws_size,
                              hipStream_t stream) {
    const float* xc     = (const float*)d_in[0];
    const float* xp     = (const float*)d_in[1];
    const int*   esrc   = (const int*)d_in[2];
    const int*   edst   = (const int*)d_in[3];
    const float* w_clin = (const float*)d_in[4];
    const float* b_clin = (const float*)d_in[5];
    const float* w_plin = (const float*)d_in[6];
    const float* b_plin = (const float*)d_in[7];
    const float* wl1_cp = (const float*)d_in[8];
    const float* wr1_cp = (const float*)d_in[9];
    const float* wl1_pc = (const float*)d_in[10];
    const float* wr1_pc = (const float*)d_in[11];
    const float* wl2_cp = (const float*)d_in[12];
    const float* wr2_cp = (const float*)d_in[13];
    const float* wl2_pc = (const float*)d_in[14];
    const float* wr2_pc = (const float*)d_in[15];
    const float* bl1_cp = (const float*)d_in[16];
    const float* bl1_pc = (const float*)d_in[17];
    const float* bl2_cp = (const float*)d_in[18];
    const float* bl2_pc = (const float*)d_in[19];
    const float* w_ih_c = (const float*)d_in[20];
    const float* w_hh_c = (const float*)d_in[21];
    const float* w_ih_p = (const float*)d_in[22];
    const float* w_hh_p = (const float*)d_in[23];
    const float* b_ih_c = (const float*)d_in[24];
    const float* b_hh_c = (const float*)d_in[25];
    const float* b_ih_p = (const float*)d_in[26];
    const float* b_hh_p = (const float*)d_in[27];

    float* ws      = (float*)d_ws;
    float* hp_all  = ws;
    float* hc_all  = hp_all + (size_t)TT * NPN * HH;
    float* hp1A    = hc_all + (size_t)TT * NCN * HH;
    float* hc1A    = hp1A + (size_t)NPN * HH;
    float* hp1B    = hc1A + (size_t)NCN * HH;
    float* hc1B    = hp1B + (size_t)NPN * HH;
    int*   cntP_all = (int*)(hc1B + (size_t)NCN * HH);
    int*   cntC_all = cntP_all + (size_t)TT * NPN;
    int*   listP_all = cntC_all + (size_t)TT * NCN;
    int*   listC_all = listP_all + (size_t)TT * NPN * CAPP;

    unsigned short* fw = (unsigned short*)(listC_all + (size_t)TT * NCN * CAPC);
    const int SB = 65536;
    const int GB = 196608;
    unsigned short* blob_s1cp = fw;
    unsigned short* blob_s1pc = blob_s1cp + SB;
    unsigned short* blob_s2cp = blob_s1pc + SB;
    unsigned short* blob_s2pc = blob_s2cp + SB;
    unsigned short* blob_gp   = blob_s2pc + SB;
    unsigned short* blob_gc   = blob_gp + GB;
    unsigned short* blob_lc   = blob_gc + GB;
    unsigned short* blob_lp   = blob_lc + 8192;

    float* h_c = (float*)d_out;
    float* h_p = h_c + (size_t)NCN * HH;

    {
        const int B = 256;
        int gs = (HH * HH + B - 1) / B;
        sage_wprep<<<gs, B, 0, stream>>>(wl1_cp, wr1_cp, blob_s1cp);
        sage_wprep<<<gs, B, 0, stream>>>(wl1_pc, wr1_pc, blob_s1pc);
        sage_wprep<<<gs, B, 0, stream>>>(wl2_cp, wr2_cp, blob_s2cp);
        sage_wprep<<<gs, B, 0, stream>>>(wl2_pc, wr2_pc, blob_s2pc);
        int gg = (3 * HH * HH + B - 1) / B;
        gru_wprep<<<gg, B, 0, stream>>>(w_ih_p, w_hh_p, blob_gp);
        gru_wprep<<<gg, B, 0, stream>>>(w_ih_c, w_hh_c, blob_gc);
        lin_wprep<<<(HH * 32 + B - 1) / B, B, 0, stream>>>(w_clin, blob_lc, 32);
        lin_wprep<<<(HH * 64 + B - 1) / B, B, 0, stream>>>(w_plin, blob_lp, 64);
    }

    hipMemsetAsync(d_out, 0, (size_t)out_size * sizeof(float), stream);
    hipMemsetAsync(cntP_all, 0, (size_t)TT * (NPN + NCN) * sizeof(int), stream);

    build_kernel<<<(TT * EE + 255) / 256, 256, 0, stream>>>(esrc, edst, cntP_all, cntC_all,
                                                            listP_all, listC_all);
    linproj_mfma<32><<<(TT * NCN + 31) / 32, 256, 0, stream>>>(xc, blob_lc, b_clin, hc_all, TT * NCN);
    linproj_mfma<64><<<(TT * NPN + 31) / 32, 256, 0, stream>>>(xp, blob_lp, b_plin, hp_all, TT * NPN);

    const int gP64 = (NPN + 63) / 64, gC64 = (NCN + 63) / 64;

    for (int k = 0; k <= TT; ++k) {
        int hasG = (k >= 1), hasS = (k < TT);
        int t_g = hasG ? (k - 1) : 0;
        int t_s = hasS ? k : 0;
        int bndGC = hasG ? gC64 : 0;
        int bndSC = bndGC + (hasS ? gC64 : 0);
        int bndGP = bndSC + (hasG ? gP64 : 0);
        int grid  = bndGP + (hasS ? gP64 : 0);
        pair_kernel<<<grid, 1024, 0, stream>>>(
            bndGC, bndSC, bndGP,
            cntP_all, cntC_all, listP_all, listC_all,
            hp_all, hc_all, hp1A, hc1A, hp1B, hc1B,
            t_g, t_s,
            blob_s1cp, bl1_cp, blob_s1pc, bl1_pc,
            blob_s2cp, bl2_cp, blob_s2pc, bl2_pc,
            blob_gp, b_ih_p, b_hh_p,
            blob_gc, b_ih_c, b_hh_c,
            h_c, h_p);
    }
}

// Round 20
// 634.863 us; speedup vs baseline: 1.2419x; 1.0876x over previous
//
#include <hip/hip_runtime.h>

#define NCN 3000
#define NPN 30000
#define TT 8
#define EE 64000
#define HH 128
#define CAPP 24
#define CAPC 64

typedef __attribute__((ext_vector_type(8))) short bf16x8;
typedef __attribute__((ext_vector_type(4))) float f32x4;

__device__ inline unsigned short f2bf(float f) {
    unsigned u = __float_as_uint(f);
    u += 0x7FFF + ((u >> 16) & 1);
    return (unsigned short)(u >> 16);
}
__device__ inline float bf2f(unsigned short h) {
    return __uint_as_float(((unsigned)h) << 16);
}
__device__ inline void split8(const float4 a, const float4 b, bf16x8& hi, bf16x8& lo) {
    float v[8] = {a.x, a.y, a.z, a.w, b.x, b.y, b.z, b.w};
#pragma unroll
    for (int i = 0; i < 8; ++i) {
        unsigned short hs = f2bf(v[i]);
        float rem = v[i] - bf2f(hs);
        hi[i] = (short)hs;
        lo[i] = (short)f2bf(rem);
    }
}
__device__ inline void add4(float4& a, const float4 b) {
    a.x += b.x; a.y += b.y; a.z += b.z; a.w += b.w;
}

// ---- linproj weight pack ----------------------------------------------------
__global__ void lin_wprep(const float* __restrict__ w, unsigned short* __restrict__ blob,
                          int K) {
    int idx = blockIdx.x * blockDim.x + threadIdx.x;
    if (idx >= HH * K) return;
    int n = idx / K, k = idx - n * K;
    int nt = n >> 4, nl = n & 15;
    int kc = k >> 5, kg = (k >> 3) & 3, kj = k & 7;
    int KC = K >> 5;
    int base = (nt * KC + kc) * 1024 + (kg * 16 + nl) * 8 + kj;
    float f = w[idx];
    unsigned short hi = f2bf(f), lo = f2bf(f - bf2f(hi));
    blob[base] = hi;
    blob[base + 512] = lo;
}

// ---- SAGE weight pack -------------------------------------------------------
__global__ void sage_wprep(const float* __restrict__ wl, const float* __restrict__ wr,
                           unsigned short* __restrict__ blob) {
    int idx = blockIdx.x * blockDim.x + threadIdx.x;
    if (idx >= HH * HH) return;
    int n = idx >> 7, k = idx & 127;
    int jt = n >> 4, nl = n & 15;
    int kc = k >> 5, kg = (k >> 3) & 3, kj = k & 7;
    int base = (jt * 4 + kc) * 2048 + (kg * 16 + nl) * 8 + kj;
    float f = wl[idx];
    unsigned short hi = f2bf(f), lo = f2bf(f - bf2f(hi));
    blob[base] = hi;
    blob[base + 512] = lo;
    f = wr[idx];
    hi = f2bf(f); lo = f2bf(f - bf2f(hi));
    blob[base + 1024] = hi;
    blob[base + 1536] = lo;
}

// ---- GRU weight pack ---------------------------------------------------------
__global__ void gru_wprep(const float* __restrict__ wih, const float* __restrict__ whh,
                          unsigned short* __restrict__ blob) {
    int idx = blockIdx.x * blockDim.x + threadIdx.x;
    if (idx >= 3 * HH * HH) return;
    int n = idx >> 7, k = idx & 127;
    int gate = n >> 7, j128 = n & 127;
    int jt = j128 >> 4, nl = j128 & 15;
    int kc = k >> 5, kg = (k >> 3) & 3, kj = k & 7;
    int base = (jt * 4 + kc) * 6144 + gate * 2048 + (kg * 16 + nl) * 8 + kj;
    float f = wih[idx];
    unsigned short hi = f2bf(f), lo = f2bf(f - bf2f(hi));
    blob[base] = hi;
    blob[base + 512] = lo;
    f = whh[idx];
    hi = f2bf(f); lo = f2bf(f - bf2f(hi));
    blob[base + 1024] = hi;
    blob[base + 1536] = lo;
}

// ---------------- input projection via split-bf16 MFMA -----------------------
template<int K>
__global__ __launch_bounds__(256, 4)
void linproj_mfma(const float* __restrict__ x, const unsigned short* __restrict__ blob,
                  const float* __restrict__ b, float* __restrict__ out, int N) {
    const int SLOTS = K / 8;
    const int KC = K / 32;
    __shared__ unsigned short lds[2 * 32 * K];
    int i0 = blockIdx.x * 32;
    int tid = threadIdx.x;
    if (tid * 8 < 32 * K) {
        int linear = tid * 8;
        int r = linear / K, k0 = linear % K;
        int row = i0 + r; if (row >= N) row = N - 1;
        float4 a = *(const float4*)&x[(size_t)row * K + k0];
        float4 b4 = *(const float4*)&x[(size_t)row * K + k0 + 4];
        bf16x8 hi, lo;
        split8(a, b4, hi, lo);
        int dst8 = (r * SLOTS + ((k0 >> 3) ^ (r & (SLOTS - 1)))) * 8;
        *(bf16x8*)&lds[dst8] = hi;
        *(bf16x8*)&lds[32 * K + dst8] = lo;
    }
    __syncthreads();
    int wid = tid >> 6, lane = tid & 63;
    int jt0 = wid * 2;
    f32x4 acc[2][2];
#pragma unroll
    for (int a = 0; a < 2; ++a)
#pragma unroll
        for (int m = 0; m < 2; ++m) acc[a][m] = (f32x4){0.f, 0.f, 0.f, 0.f};
#pragma unroll
    for (int kc = 0; kc < KC; ++kc) {
        bf16x8 ah[2], al[2];
#pragma unroll
        for (int mt = 0; mt < 2; ++mt) {
            int rl = mt * 16 + (lane & 15);
            int slot = (kc * 4 + (lane >> 4)) ^ (rl & (SLOTS - 1));
            int aoff = (rl * SLOTS + slot) * 8;
            ah[mt] = *(const bf16x8*)&lds[aoff];
            al[mt] = *(const bf16x8*)&lds[32 * K + aoff];
        }
#pragma unroll
        for (int jj = 0; jj < 2; ++jj) {
            int bbase = ((jt0 + jj) * KC + kc) * 1024 + lane * 8;
            bf16x8 f0 = *(const bf16x8*)&blob[bbase];
            bf16x8 f1 = *(const bf16x8*)&blob[bbase + 512];
#pragma unroll
            for (int mt = 0; mt < 2; ++mt) {
                acc[jj][mt] = __builtin_amdgcn_mfma_f32_16x16x32_bf16(ah[mt], f0, acc[jj][mt], 0, 0, 0);
                acc[jj][mt] = __builtin_amdgcn_mfma_f32_16x16x32_bf16(al[mt], f0, acc[jj][mt], 0, 0, 0);
                acc[jj][mt] = __builtin_amdgcn_mfma_f32_16x16x32_bf16(ah[mt], f1, acc[jj][mt], 0, 0, 0);
            }
        }
    }
#pragma unroll
    for (int jj = 0; jj < 2; ++jj) {
        int j = (jt0 + jj) * 16 + (lane & 15);
        float bv = b[j];
#pragma unroll
        for (int mt = 0; mt < 2; ++mt) {
#pragma unroll
            for (int q = 0; q < 4; ++q) {
                int r_loc = mt * 16 + (lane >> 4) * 4 + q;
                int row = i0 + r_loc;
                if (row < N) out[(size_t)row * HH + j] = acc[jj][mt][q] + bv;
            }
        }
    }
}

// ---------------- edge bucket build, all timesteps ---------------------------
__global__ void build_kernel(const int* __restrict__ es, const int* __restrict__ ed,
                             int* __restrict__ cntP, int* __restrict__ cntC,
                             int* __restrict__ listP, int* __restrict__ listC) {
    int g = blockIdx.x * 256 + threadIdx.x;
    if (g >= TT * EE) return;
    int t = g / EE;
    int s = es[g], d = ed[g];
    int pP = atomicAdd(&cntP[t * NPN + d], 1);
    if (pP < CAPP) listP[((size_t)t * NPN + d) * CAPP + pP] = s;
    int pC = atomicAdd(&cntC[t * NCN + s], 1);
    if (pC < CAPC) listC[((size_t)t * NCN + s) * CAPC + pC] = d;
}

// ---- staging (512 threads): gather-mean + self row -> split-bf16 LDS --------
__device__ inline void stage512(unsigned short* lds, const int* cnt, const int* list,
                                int CAP, const float* gsrc, const float* hin,
                                int i0, int N, int tid) {
    int r = tid >> 4, k0 = (tid & 15) * 8;
    int row = i0 + r; if (row >= N) row = N - 1;
    float4 ha = *(const float4*)&hin[(size_t)row * HH + k0];
    float4 hb = *(const float4*)&hin[(size_t)row * HH + k0 + 4];
    int ntru = cnt[row];
    int n = ntru > CAP ? CAP : ntru;
    const int* lst = &list[(size_t)row * CAP];
    float4 a0 = {0,0,0,0}, b0 = {0,0,0,0}, a1 = {0,0,0,0}, b1 = {0,0,0,0};
    float4 a2 = {0,0,0,0}, b2 = {0,0,0,0}, a3 = {0,0,0,0}, b3 = {0,0,0,0};
    int e = 0;
    for (; e + 4 <= n; e += 4) {
        int4 ss = *(const int4*)&lst[e];
        const float4* p0 = (const float4*)&gsrc[(size_t)ss.x * HH + k0];
        const float4* p1 = (const float4*)&gsrc[(size_t)ss.y * HH + k0];
        const float4* p2 = (const float4*)&gsrc[(size_t)ss.z * HH + k0];
        const float4* p3 = (const float4*)&gsrc[(size_t)ss.w * HH + k0];
        float4 u0 = p0[0], v0 = p0[1];
        float4 u1 = p1[0], v1 = p1[1];
        float4 u2 = p2[0], v2 = p2[1];
        float4 u3 = p3[0], v3 = p3[1];
        add4(a0, u0); add4(b0, v0);
        add4(a1, u1); add4(b1, v1);
        add4(a2, u2); add4(b2, v2);
        add4(a3, u3); add4(b3, v3);
    }
    for (; e < n; ++e) {
        int s = lst[e];
        const float4* p0 = (const float4*)&gsrc[(size_t)s * HH + k0];
        float4 u0 = p0[0], v0 = p0[1];
        add4(a0, u0); add4(b0, v0);
    }
    add4(a0, a1); add4(b0, b1);
    add4(a2, a3); add4(b2, b3);
    add4(a0, a2); add4(b0, b2);
    float inv = 1.0f / fmaxf((float)ntru, 1.0f);
    a0.x *= inv; a0.y *= inv; a0.z *= inv; a0.w *= inv;
    b0.x *= inv; b0.y *= inv; b0.z *= inv; b0.w *= inv;
    int dst8 = (r * 16 + ((k0 >> 3) ^ (r & 7))) * 8;
    bf16x8 hi, lo;
    split8(a0, b0, hi, lo);
    *(bf16x8*)&lds[dst8] = hi;
    *(bf16x8*)&lds[4096 + dst8] = lo;
    split8(ha, hb, hi, lo);
    *(bf16x8*)&lds[8192 + dst8] = hi;
    *(bf16x8*)&lds[12288 + dst8] = lo;
}

// ========= PAIR kernel: sage2+gru(t_gru)  ∥  sage layer-1(t_sage) ============
// 512 threads / 8 waves; wave wid owns jt = wid. Roles: [gru-C|sage-C|gru-P|sage-P].
// Latency hiding: hprev preload at top; sage/gru B-blob quads prefetched one
// step ahead.
__global__ __launch_bounds__(512, 2)
void pair_kernel(int bndGC, int bndSC, int bndGP,
                 const int* __restrict__ cntP_all, const int* __restrict__ cntC_all,
                 const int* __restrict__ listP_all, const int* __restrict__ listC_all,
                 const float* __restrict__ hp_all, const float* __restrict__ hc_all,
                 float* __restrict__ hp1A, float* __restrict__ hc1A,
                 float* __restrict__ hp1B, float* __restrict__ hc1B,
                 int t_gru, int t_sage,
                 const unsigned short* __restrict__ blob_s1cp, const float* __restrict__ bl1_cp,
                 const unsigned short* __restrict__ blob_s1pc, const float* __restrict__ bl1_pc,
                 const unsigned short* __restrict__ blob_s2cp, const float* __restrict__ bl2_cp,
                 const unsigned short* __restrict__ blob_s2pc, const float* __restrict__ bl2_pc,
                 const unsigned short* __restrict__ blob_gp,
                 const float* __restrict__ b_ih_p, const float* __restrict__ b_hh_p,
                 const unsigned short* __restrict__ blob_gc,
                 const float* __restrict__ b_ih_c, const float* __restrict__ b_hh_c,
                 float* __restrict__ h_c, float* __restrict__ h_p) {
    __shared__ unsigned short lds[4 * 4096];
    int bid = blockIdx.x;
    bool isGru, isC;
    int idx;
    if (bid < bndGC)      { isGru = true;  isC = true;  idx = bid; }
    else if (bid < bndSC) { isGru = false; isC = true;  idx = bid - bndGC; }
    else if (bid < bndGP) { isGru = true;  isC = false; idx = bid - bndSC; }
    else                  { isGru = false; isC = false; idx = bid - bndGP; }

    float* hp1_g = (t_gru & 1) ? hp1B : hp1A;
    float* hc1_g = (t_gru & 1) ? hc1B : hc1A;
    float* hp1_s = (t_sage & 1) ? hp1B : hp1A;
    float* hc1_s = (t_sage & 1) ? hc1B : hc1A;

    const int* cnt; const int* list; int CAP;
    const float* gsrc; const float* hin;
    const unsigned short* sblob; const float* sbl;
    const unsigned short* gblob; const float* bih; const float* bhh;
    float* outp;
    int N, i0 = idx * 32;
    if (isGru) {
        if (isC) {
            cnt = cntC_all + (size_t)t_gru * NCN;
            list = listC_all + (size_t)t_gru * NCN * CAPC; CAP = CAPC;
            gsrc = hp1_g; hin = hc1_g;
            sblob = blob_s2pc; sbl = bl2_pc;
            gblob = blob_gc; bih = b_ih_c; bhh = b_hh_c;
            outp = h_c; N = NCN;
        } else {
            cnt = cntP_all + (size_t)t_gru * NPN;
            list = listP_all + (size_t)t_gru * NPN * CAPP; CAP = CAPP;
            gsrc = hc1_g; hin = hp1_g;
            sblob = blob_s2cp; sbl = bl2_cp;
            gblob = blob_gp; bih = b_ih_p; bhh = b_hh_p;
            outp = h_p; N = NPN;
        }
    } else {
        const float* hp_t = hp_all + (size_t)t_sage * NPN * HH;
        const float* hc_t = hc_all + (size_t)t_sage * NCN * HH;
        if (isC) {
            cnt = cntC_all + (size_t)t_sage * NCN;
            list = listC_all + (size_t)t_sage * NCN * CAPC; CAP = CAPC;
            gsrc = hp_t; hin = hc_t;
            sblob = blob_s1pc; sbl = bl1_pc;
            gblob = nullptr; bih = nullptr; bhh = nullptr;
            outp = hc1_s; N = NCN;
        } else {
            cnt = cntP_all + (size_t)t_sage * NPN;
            list = listP_all + (size_t)t_sage * NPN * CAPP; CAP = CAPP;
            gsrc = hc_t; hin = hp_t;
            sblob = blob_s1cp; sbl = bl1_cp;
            gblob = nullptr; bih = nullptr; bhh = nullptr;
            outp = hp1_s; N = NPN;
        }
    }
    int tid = threadIdx.x;
    int wid = tid >> 6, lane = tid & 63;
    int jt = wid;
    int sr = tid >> 4, sk0 = (tid & 15) * 8;

    // ---- hprev preload (gru role): issue before anything else --------------
    float4 hpre0, hpre1;
    if (isGru) {
        int row = i0 + sr; if (row >= N) row = N - 1;
        hpre0 = *(const float4*)&outp[(size_t)row * HH + sk0];
        hpre1 = *(const float4*)&outp[(size_t)row * HH + sk0 + 4];
    }

    stage512(lds, cnt, list, CAP, gsrc, hin, i0, N, tid);

    // ---- prefetch sage blob quad for kc=0 (completes during barrier) -------
    bf16x8 sp0, sp1, sp2, sp3;
    {
        int nb = (jt * 4 + 0) * 2048 + lane * 8;
        sp0 = *(const bf16x8*)&sblob[nb];
        sp1 = *(const bf16x8*)&sblob[nb + 512];
        sp2 = *(const bf16x8*)&sblob[nb + 1024];
        sp3 = *(const bf16x8*)&sblob[nb + 1536];
    }
    __syncthreads();

    // ---- sage MFMA with B double-buffer ------------------------------------
    f32x4 acc[2];
    acc[0] = (f32x4){0.f, 0.f, 0.f, 0.f};
    acc[1] = (f32x4){0.f, 0.f, 0.f, 0.f};
#pragma unroll
    for (int kc = 0; kc < 4; ++kc) {
        bf16x8 c0 = sp0, c1 = sp1, c2 = sp2, c3 = sp3;
        if (kc < 3) {
            int nb = (jt * 4 + kc + 1) * 2048 + lane * 8;
            sp0 = *(const bf16x8*)&sblob[nb];
            sp1 = *(const bf16x8*)&sblob[nb + 512];
            sp2 = *(const bf16x8*)&sblob[nb + 1024];
            sp3 = *(const bf16x8*)&sblob[nb + 1536];
        }
#pragma unroll
        for (int mt = 0; mt < 2; ++mt) {
            int rl = mt * 16 + (lane & 15);
            int aoff = (rl * 16 + ((kc * 4 + (lane >> 4)) ^ (rl & 7))) * 8;
            bf16x8 amh = *(const bf16x8*)&lds[aoff];
            bf16x8 aml = *(const bf16x8*)&lds[4096 + aoff];
            bf16x8 ahh = *(const bf16x8*)&lds[8192 + aoff];
            bf16x8 ahl = *(const bf16x8*)&lds[12288 + aoff];
            acc[mt] = __builtin_amdgcn_mfma_f32_16x16x32_bf16(amh, c0, acc[mt], 0, 0, 0);
            acc[mt] = __builtin_amdgcn_mfma_f32_16x16x32_bf16(aml, c0, acc[mt], 0, 0, 0);
            acc[mt] = __builtin_amdgcn_mfma_f32_16x16x32_bf16(amh, c1, acc[mt], 0, 0, 0);
            acc[mt] = __builtin_amdgcn_mfma_f32_16x16x32_bf16(ahh, c2, acc[mt], 0, 0, 0);
            acc[mt] = __builtin_amdgcn_mfma_f32_16x16x32_bf16(ahl, c2, acc[mt], 0, 0, 0);
            acc[mt] = __builtin_amdgcn_mfma_f32_16x16x32_bf16(ahh, c3, acc[mt], 0, 0, 0);
        }
    }
    int j = jt * 16 + (lane & 15);

    if (!isGru) {
        float bv = sbl[j];
#pragma unroll
        for (int mt = 0; mt < 2; ++mt) {
#pragma unroll
            for (int q = 0; q < 4; ++q) {
                int r_loc = mt * 16 + (lane >> 4) * 4 + q;
                int row = i0 + r_loc;
                if (row >= N) continue;
                float v = fmaxf(acc[mt][q] + bv, 0.0f);
                outp[(size_t)row * HH + j] = v;
            }
        }
        return;
    }

    // ---- GRU phase C: x = acc + bias into LDS 0/1; hprev (preloaded) into 2/3
    __syncthreads();
    {
        float bv = sbl[j];
#pragma unroll
        for (int mt = 0; mt < 2; ++mt) {
#pragma unroll
            for (int q = 0; q < 4; ++q) {
                int r_loc = mt * 16 + (lane >> 4) * 4 + q;
                float v = acc[mt][q] + bv;
                unsigned short hi = f2bf(v);
                unsigned short lo = f2bf(v - bf2f(hi));
                int off = (r_loc * 16 + ((j >> 3) ^ (r_loc & 7))) * 8 + (j & 7);
                lds[off] = hi;
                lds[4096 + off] = lo;
            }
        }
        int dst8 = (sr * 16 + ((sk0 >> 3) ^ (sr & 7))) * 8;
        bf16x8 hi, lo;
        split8(hpre0, hpre1, hi, lo);
        *(bf16x8*)&lds[8192 + dst8] = hi;
        *(bf16x8*)&lds[12288 + dst8] = lo;
    }
    // prefetch first gru quad (kc=0, gate r) — completes during barrier
    bf16x8 cq0, cq1, cq2, cq3;
    {
        int nb = (jt * 4 + 0) * 6144 + lane * 8;
        cq0 = *(const bf16x8*)&gblob[nb];
        cq1 = *(const bf16x8*)&gblob[nb + 512];
        cq2 = *(const bf16x8*)&gblob[nb + 1024];
        cq3 = *(const bf16x8*)&gblob[nb + 1536];
    }
    __syncthreads();

    // ---- GRU MFMA: (kc,gate) steps with one-quad lookahead -----------------
    f32x4 ar[2], az[2], an[2], ahn[2];
#pragma unroll
    for (int m = 0; m < 2; ++m) {
        ar[m] = (f32x4){0.f, 0.f, 0.f, 0.f};
        az[m] = (f32x4){0.f, 0.f, 0.f, 0.f};
        an[m] = (f32x4){0.f, 0.f, 0.f, 0.f};
        ahn[m] = (f32x4){0.f, 0.f, 0.f, 0.f};
    }
#pragma unroll
    for (int kc = 0; kc < 4; ++kc) {
        bf16x8 axh[2], axl[2], ahh[2], ahl[2];
#pragma unroll
        for (int mt = 0; mt < 2; ++mt) {
            int rl = mt * 16 + (lane & 15);
            int aoff = (rl * 16 + ((kc * 4 + (lane >> 4)) ^ (rl & 7))) * 8;
            axh[mt] = *(const bf16x8*)&lds[aoff];
            axl[mt] = *(const bf16x8*)&lds[4096 + aoff];
            ahh[mt] = *(const bf16x8*)&lds[8192 + aoff];
            ahl[mt] = *(const bf16x8*)&lds[12288 + aoff];
        }
        int bbase = (jt * 4 + kc) * 6144 + lane * 8;
#pragma unroll
        for (int g = 0; g < 3; ++g) {
            bf16x8 nq0, nq1, nq2, nq3;
            if (!(kc == 3 && g == 2)) {
                int nb = (g < 2) ? (bbase + (g + 1) * 2048)
                                 : ((jt * 4 + kc + 1) * 6144 + lane * 8);
                nq0 = *(const bf16x8*)&gblob[nb];
                nq1 = *(const bf16x8*)&gblob[nb + 512];
                nq2 = *(const bf16x8*)&gblob[nb + 1024];
                nq3 = *(const bf16x8*)&gblob[nb + 1536];
            }
#pragma unroll
            for (int mt = 0; mt < 2; ++mt) {
                if (g == 2) {
                    an[mt] = __builtin_amdgcn_mfma_f32_16x16x32_bf16(axh[mt], cq0, an[mt], 0, 0, 0);
                    an[mt] = __builtin_amdgcn_mfma_f32_16x16x32_bf16(axl[mt], cq0, an[mt], 0, 0, 0);
                    an[mt] = __builtin_amdgcn_mfma_f32_16x16x32_bf16(axh[mt], cq1, an[mt], 0, 0, 0);
                    ahn[mt] = __builtin_amdgcn_mfma_f32_16x16x32_bf16(ahh[mt], cq2, ahn[mt], 0, 0, 0);
                    ahn[mt] = __builtin_amdgcn_mfma_f32_16x16x32_bf16(ahl[mt], cq2, ahn[mt], 0, 0, 0);
                    ahn[mt] = __builtin_amdgcn_mfma_f32_16x16x32_bf16(ahh[mt], cq3, ahn[mt], 0, 0, 0);
                } else {
                    f32x4& a = (g == 0) ? ar[mt] : az[mt];
                    a = __builtin_amdgcn_mfma_f32_16x16x32_bf16(axh[mt], cq0, a, 0, 0, 0);
                    a = __builtin_amdgcn_mfma_f32_16x16x32_bf16(axl[mt], cq0, a, 0, 0, 0);
                    a = __builtin_amdgcn_mfma_f32_16x16x32_bf16(axh[mt], cq1, a, 0, 0, 0);
                    a = __builtin_amdgcn_mfma_f32_16x16x32_bf16(ahh[mt], cq2, a, 0, 0, 0);
                    a = __builtin_amdgcn_mfma_f32_16x16x32_bf16(ahl[mt], cq2, a, 0, 0, 0);
                    a = __builtin_amdgcn_mfma_f32_16x16x32_bf16(ahh[mt], cq3, a, 0, 0, 0);
                }
            }
            if (!(kc == 3 && g == 2)) {
                cq0 = nq0; cq1 = nq1; cq2 = nq2; cq3 = nq3;
            }
        }
    }
    {
        float br = bih[j] + bhh[j];
        float bz = bih[HH + j] + bhh[HH + j];
        float bn_i = bih[2 * HH + j];
        float bn_h = bhh[2 * HH + j];
#pragma unroll
        for (int mt = 0; mt < 2; ++mt) {
#pragma unroll
            for (int q = 0; q < 4; ++q) {
                int r_loc = mt * 16 + (lane >> 4) * 4 + q;
                int row = i0 + r_loc;
                if (row >= N) continue;
                float pr = ar[mt][q] + br;
                float pz = az[mt][q] + bz;
                float pn = an[mt][q] + bn_i;
                float phn = ahn[mt][q] + bn_h;
                float rg = 1.0f / (1.0f + __expf(-pr));
                float zg = 1.0f / (1.0f + __expf(-pz));
                float ng = tanhf(pn + rg * phn);
                int eo = (r_loc * 16 + ((j >> 3) ^ (r_loc & 7))) * 8 + (j & 7);
                float hprev = bf2f(lds[8192 + eo]) + bf2f(lds[12288 + eo]);
                outp[(size_t)row * HH + j] = (1.0f - zg) * ng + zg * hprev;
            }
        }
    }
}

extern "C" void kernel_launch(void* const* d_in, const int* in_sizes, int n_in,
                              void* d_out, int out_size, void* d_ws, size_t ws_size,
                              hipStream_t stream) {
    const float* xc     = (const float*)d_in[0];
    const float* xp     = (const float*)d_in[1];
    const int*   esrc   = (const int*)d_in[2];
    const int*   edst   = (const int*)d_in[3];
    const float* w_clin = (const float*)d_in[4];
    const float* b_clin = (const float*)d_in[5];
    const float* w_plin = (const float*)d_in[6];
    const float* b_plin = (const float*)d_in[7];
    const float* wl1_cp = (const float*)d_in[8];
    const float* wr1_cp = (const float*)d_in[9];
    const float* wl1_pc = (const float*)d_in[10];
    const float* wr1_pc = (const float*)d_in[11];
    const float* wl2_cp = (const float*)d_in[12];
    const float* wr2_cp = (const float*)d_in[13];
    const float* wl2_pc = (const float*)d_in[14];
    const float* wr2_pc = (const float*)d_in[15];
    const float* bl1_cp = (const float*)d_in[16];
    const float* bl1_pc = (const float*)d_in[17];
    const float* bl2_cp = (const float*)d_in[18];
    const float* bl2_pc = (const float*)d_in[19];
    const float* w_ih_c = (const float*)d_in[20];
    const float* w_hh_c = (const float*)d_in[21];
    const float* w_ih_p = (const float*)d_in[22];
    const float* w_hh_p = (const float*)d_in[23];
    const float* b_ih_c = (const float*)d_in[24];
    const float* b_hh_c = (const float*)d_in[25];
    const float* b_ih_p = (const float*)d_in[26];
    const float* b_hh_p = (const float*)d_in[27];

    float* ws      = (float*)d_ws;
    float* hp_all  = ws;
    float* hc_all  = hp_all + (size_t)TT * NPN * HH;
    float* hp1A    = hc_all + (size_t)TT * NCN * HH;
    float* hc1A    = hp1A + (size_t)NPN * HH;
    float* hp1B    = hc1A + (size_t)NCN * HH;
    float* hc1B    = hp1B + (size_t)NPN * HH;
    int*   cntP_all = (int*)(hc1B + (size_t)NCN * HH);
    int*   cntC_all = cntP_all + (size_t)TT * NPN;
    int*   listP_all = cntC_all + (size_t)TT * NCN;
    int*   listC_all = listP_all + (size_t)TT * NPN * CAPP;

    unsigned short* fw = (unsigned short*)(listC_all + (size_t)TT * NCN * CAPC);
    const int SB = 65536;
    const int GB = 196608;
    unsigned short* blob_s1cp = fw;
    unsigned short* blob_s1pc = blob_s1cp + SB;
    unsigned short* blob_s2cp = blob_s1pc + SB;
    unsigned short* blob_s2pc = blob_s2cp + SB;
    unsigned short* blob_gp   = blob_s2pc + SB;
    unsigned short* blob_gc   = blob_gp + GB;
    unsigned short* blob_lc   = blob_gc + GB;
    unsigned short* blob_lp   = blob_lc + 8192;

    float* h_c = (float*)d_out;
    float* h_p = h_c + (size_t)NCN * HH;

    {
        const int B = 256;
        int gs = (HH * HH + B - 1) / B;
        sage_wprep<<<gs, B, 0, stream>>>(wl1_cp, wr1_cp, blob_s1cp);
        sage_wprep<<<gs, B, 0, stream>>>(wl1_pc, wr1_pc, blob_s1pc);
        sage_wprep<<<gs, B, 0, stream>>>(wl2_cp, wr2_cp, blob_s2cp);
        sage_wprep<<<gs, B, 0, stream>>>(wl2_pc, wr2_pc, blob_s2pc);
        int gg = (3 * HH * HH + B - 1) / B;
        gru_wprep<<<gg, B, 0, stream>>>(w_ih_p, w_hh_p, blob_gp);
        gru_wprep<<<gg, B, 0, stream>>>(w_ih_c, w_hh_c, blob_gc);
        lin_wprep<<<(HH * 32 + B - 1) / B, B, 0, stream>>>(w_clin, blob_lc, 32);
        lin_wprep<<<(HH * 64 + B - 1) / B, B, 0, stream>>>(w_plin, blob_lp, 64);
    }

    hipMemsetAsync(d_out, 0, (size_t)out_size * sizeof(float), stream);
    hipMemsetAsync(cntP_all, 0, (size_t)TT * (NPN + NCN) * sizeof(int), stream);

    build_kernel<<<(TT * EE + 255) / 256, 256, 0, stream>>>(esrc, edst, cntP_all, cntC_all,
                                                            listP_all, listC_all);
    linproj_mfma<32><<<(TT * NCN + 31) / 32, 256, 0, stream>>>(xc, blob_lc, b_clin, hc_all, TT * NCN);
    linproj_mfma<64><<<(TT * NPN + 31) / 32, 256, 0, stream>>>(xp, blob_lp, b_plin, hp_all, TT * NPN);

    const int gP32 = (NPN + 31) / 32, gC32 = (NCN + 31) / 32;

    for (int k = 0; k <= TT; ++k) {
        int hasG = (k >= 1), hasS = (k < TT);
        int t_g = hasG ? (k - 1) : 0;
        int t_s = hasS ? k : 0;
        int bndGC = hasG ? gC32 : 0;
        int bndSC = bndGC + (hasS ? gC32 : 0);
        int bndGP = bndSC + (hasG ? gP32 : 0);
        int grid  = bndGP + (hasS ? gP32 : 0);
        pair_kernel<<<grid, 512, 0, stream>>>(
            bndGC, bndSC, bndGP,
            cntP_all, cntC_all, listP_all, listC_all,
            hp_all, hc_all, hp1A, hc1A, hp1B, hc1B,
            t_g, t_s,
            blob_s1cp, bl1_cp, blob_s1pc, bl1_pc,
            blob_s2cp, bl2_cp, blob_s2pc, bl2_pc,
            blob_gp, b_ih_p, b_hh_p,
            blob_gc, b_ih_c, b_hh_c,
            h_c, h_p);
    }
}